// Round 11
// baseline (214.698 us; speedup 1.0000x reference)
//
#include <hip/hip_runtime.h>
#include <hip/hip_bf16.h>
#include <stdint.h>

// Problem constants
#define H_    16
#define N_    2048
#define DIM_  1024
#define DH_   64
#define NN_   2
#define J_    2050     // N + NNULL
#define JP_   2112     // 33*64, padded j (tails zeroed in prep)
#define B_    2
#define M_    4096     // B * N
#define NSEG_ 84       // sum over qt of ceil((qt+2)/8)  (64-row q-tiles)

#define S8L_  11.541560327111707f   // 8 * log2(e), folded into Qn at Q-GEMM epilogue
#define LOG2E_ 1.4426950408889634f

typedef unsigned short u16;
typedef unsigned int u32;
typedef short bf16x8 __attribute__((ext_vector_type(8)));
typedef float f32x4 __attribute__((ext_vector_type(4)));

__device__ __forceinline__ u16 f2b(float f) {
  union { float f; unsigned int i; } v; v.f = f;
  unsigned int r = v.i + 0x7fffu + ((v.i >> 16) & 1u);   // RNE
  return (u16)(r >> 16);
}
__device__ __forceinline__ float lo2f(u32 u) {
  union { u32 i; float f; } v; v.i = u << 16; return v.f;
}
__device__ __forceinline__ float hi2f(u32 u) {
  union { u32 i; float f; } v; v.i = u & 0xffff0000u; return v.f;
}
__device__ __forceinline__ void unp8(const uint4 u, float* d) {
  d[0] = lo2f(u.x); d[1] = hi2f(u.x); d[2] = lo2f(u.y); d[3] = hi2f(u.y);
  d[4] = lo2f(u.z); d[5] = hi2f(u.z); d[6] = lo2f(u.w); d[7] = hi2f(u.w);
}
// packed fp32x2 -> bf16x2 (single v_cvt_pk_bf16_f32)
__device__ __forceinline__ u32 pk2(float a, float b) {
  union { __hip_bfloat162 h; u32 u; } x;
  x.h = __float22bfloat162_rn(make_float2(a, b));
  return x.u;
}
// async global->LDS DMA, 16B/lane; LDS dest = wave-uniform base + lane*16
__device__ __forceinline__ void dma16(const u16* g, u16* l) {
  __builtin_amdgcn_global_load_lds(
      (const __attribute__((address_space(1))) u32*)(const void*)g,
      (__attribute__((address_space(3))) u32*)(void*)l, 16, 0, 0);
}

// ---------------- fused prep kernel ----------------
// bx <  128 : transpose+cast Wq/Wkv/Wout (fp32 RxC -> bf16 CxR)
// bx in [128,256): LayerNorm row (bx-128)*32+by -> xn, and bf16 cast -> xbf
// bx == 256 : null-kv rows j<2 -> Kb (l2norm*ks) and VTp (pos=j at c=0)
// bx == 257 : zero Kb rows j in [2048,2112) (j=2048,2049 overwritten by KV-GEMM after)
// bx == 258 : zero VTp chunk c=32 (pos 0,1 overwritten by KV-GEMM after)
__global__ __launch_bounds__(256) void prep_k(const float* __restrict__ x,
                                              const float* __restrict__ g,
                                              const float* __restrict__ bb,
                                              const float* __restrict__ Wq,
                                              const float* __restrict__ Wkv,
                                              const float* __restrict__ Wout,
                                              const float* __restrict__ nkv,
                                              const float* __restrict__ ks,
                                              u16* __restrict__ xn,
                                              u16* __restrict__ xbf,
                                              u16* __restrict__ WqT,
                                              u16* __restrict__ WkvT,
                                              u16* __restrict__ WoutT,
                                              u16* __restrict__ Kb,
                                              u16* __restrict__ VTp) {
  __shared__ float tile[32][33];
  __shared__ float red[8];
  int bx = blockIdx.x, by = blockIdx.y;
  int t = threadIdx.x;
  if (bx < 128) {
    // ---- weight transpose+cast ----
    const float* in; u16* out; int C; int cx;
    if (bx < 32)      { in = Wq;   out = WqT;   C = 1024; cx = bx; }
    else if (bx < 96) { in = Wkv;  out = WkvT;  C = 2048; cx = bx - 32; }
    else              { in = Wout; out = WoutT; C = 1024; cx = bx - 96; }
    const int R = 1024;
    int tx = t & 31, ty = t >> 5;   // 32 x 8
    int c0 = cx * 32, r0 = by * 32;
    #pragma unroll
    for (int i = 0; i < 32; i += 8)
      tile[ty + i][tx] = in[(size_t)(r0 + ty + i) * C + c0 + tx];
    __syncthreads();
    #pragma unroll
    for (int i = 0; i < 32; i += 8)
      out[(size_t)(c0 + ty + i) * R + r0 + tx] = f2b(tile[tx][ty + i]);
  } else if (bx < 256) {
    // ---- LayerNorm ----
    int row = (bx - 128) * 32 + by;
    float4 rw = *(const float4*)(x + (size_t)row * DIM_ + t * 4);
    float v0 = rw.x, v1 = rw.y, v2 = rw.z, v3 = rw.w;
    uint2 cw;
    cw.x = pk2(v0, v1);
    cw.y = pk2(v2, v3);
    *(uint2*)(xbf + (size_t)row * DIM_ + t * 4) = cw;
    float s = v0 + v1 + v2 + v3;
    float ss = v0 * v0 + v1 * v1 + v2 * v2 + v3 * v3;
    #pragma unroll
    for (int o = 32; o; o >>= 1) { s += __shfl_xor(s, o, 64); ss += __shfl_xor(ss, o, 64); }
    int lane = t & 63, w = t >> 6;
    if (lane == 0) { red[w] = s; red[4 + w] = ss; }
    __syncthreads();
    float S = red[0] + red[1] + red[2] + red[3];
    float SS = red[4] + red[5] + red[6] + red[7];
    float mu = S * (1.0f / DIM_);
    float var = SS * (1.0f / DIM_) - mu * mu;
    float rs = rsqrtf(var + 1e-5f);
    float4 gv = *(const float4*)(g + t * 4);
    float4 bv = *(const float4*)(bb + t * 4);
    uint2 ow;
    ow.x = pk2((v0 - mu) * rs * gv.x + bv.x, (v1 - mu) * rs * gv.y + bv.y);
    ow.y = pk2((v2 - mu) * rs * gv.z + bv.z, (v3 - mu) * rs * gv.w + bv.w);
    *(uint2*)(xn + (size_t)row * DIM_ + t * 4) = ow;
  } else if (bx == 256) {
    // ---- null kv: j = 0,1 ----
    int bh = by, h = bh & 15;
    if (t < 128) {
      int j = t >> 6, d = t & 63;
      float kv = nkv[(size_t)(h * 4 + 2 * j) * 64 + d];
      float vv = nkv[(size_t)(h * 4 + 2 * j + 1) * 64 + d];
      float ssp = kv * kv;
      #pragma unroll
      for (int o = 32; o; o >>= 1) ssp += __shfl_xor(ssp, o, 64);
      float inv = 1.0f / fmaxf(sqrtf(ssp), 1e-12f);
      Kb[((size_t)bh * JP_ + j) * 64 + d] = f2b(kv * inv * ks[d]);
      VTp[((size_t)bh * 64 + d) * JP_ + j] = f2b(vv);
    }
  } else if (bx == 257) {
    // ---- zero Kb rows j in [2048, 2112) ----
    int bh = by;
    uint4 z = {0, 0, 0, 0};
    u16* dst = Kb + ((size_t)bh * JP_ + 2048) * 64 + t * 16;
    ((uint4*)dst)[0] = z;
    ((uint4*)dst)[1] = z;
  } else {
    // ---- zero VTp chunk c=32 ----
    int bh = by;
    uint4 z = {0, 0, 0, 0};
    int d = t >> 2, p0 = (t & 3) * 16;
    u16* dst = VTp + ((size_t)bh * 64 + d) * JP_ + 2048 + p0;
    ((uint4*)dst)[0] = z;
    ((uint4*)dst)[1] = z;
  }
}

// ---------------- fused Q + KV GEMM, 128x128 tiles, BK=64, dbuf ----------------
// nlin<256 -> Q (xn @ WqT, l2norm*qs*8log2e -> Qn); else -> KV (xbf @ WkvT;
// K cols: l2norm*ks -> Kb; V cols -> VTp permuted). 256%8==0 keeps XCD remaps bijective.
// pos(jl) = (jl>>5)*32 + ((jl>>2)&3)*8 + ((jl>>4)&1)*4 + (jl&3)   [pi inverse]
__global__ __launch_bounds__(256) void gemmqkv_k(const u16* __restrict__ xn,
                                                 const u16* __restrict__ WqT,
                                                 const u16* __restrict__ xbf,
                                                 const u16* __restrict__ WkvT,
                                                 u16* __restrict__ Qn,
                                                 u16* __restrict__ Kb,
                                                 u16* __restrict__ VTp,
                                                 const float* __restrict__ qs,
                                                 const float* __restrict__ ks) {
  __shared__ u16 As[2][128 * 64];   // 32 KB
  __shared__ u16 Bs[2][128 * 64];   // 32 KB
  const int K = 1024;
  int tid = threadIdx.x, wv = tid >> 6, lane = tid & 63;
  int fm = lane & 15, fg = lane >> 4;
  int fg4 = fg * 4;
  int wr = wv >> 1, wc = wv & 1;           // 2x2 wave grid
  int nlin = (int)blockIdx.x;
  bool isQ = nlin < 256;
  const u16* A;
  const u16* BT;
  int gx, local;
  if (isQ) { A = xn;  BT = WqT;  gx = 8;  local = nlin; }
  else     { A = xbf; BT = WkvT; gx = 16; local = nlin - 256; }
  // bijective XCD y-chunk remap within the sub-problem (local%8 == hw nlin%8)
  int mm = local >> 3;
  int row0 = ((local & 7) * 4 + mm / gx) * 128;
  int col0 = (mm % gx) * 128;
  f32x4 acc[4][4] = {};
  int srow = lane >> 3;                 // 0..7
  int skb = ((lane & 7) ^ srow) * 8;    // swizzled global k-offset (u16)
  const u16* Ag = A + (size_t)(row0 + wv * 32 + srow) * K + skb;
  const u16* Bg = BT + (size_t)(col0 + wv * 32 + srow) * K + skb;
  int fr7 = fm & 7;
  int ak0 = (fg ^ fr7) * 8;
  int ak1 = ((fg + 4) ^ fr7) * 8;
  auto stageg = [&](int k0, int buf) {
    u16* AsW = As[buf] + (wv * 32) * 64;
    u16* BsW = Bs[buf] + (wv * 32) * 64;
    dma16(Ag + k0,                    AsW);
    dma16(Ag + (size_t)8 * K + k0,    AsW + 8 * 64);
    dma16(Ag + (size_t)16 * K + k0,   AsW + 16 * 64);
    dma16(Ag + (size_t)24 * K + k0,   AsW + 24 * 64);
    dma16(Bg + k0,                    BsW);
    dma16(Bg + (size_t)8 * K + k0,    BsW + 8 * 64);
    dma16(Bg + (size_t)16 * K + k0,   BsW + 16 * 64);
    dma16(Bg + (size_t)24 * K + k0,   BsW + 24 * 64);
  };
  stageg(0, 0);
  __syncthreads();
  int cur = 0;
  for (int k0 = 0; k0 < K; k0 += 64) {
    if (k0 + 64 < K) stageg(k0 + 64, cur ^ 1);
    bf16x8 af0[4], af1[4], bf0[4], bf1[4];
    #pragma unroll
    for (int mt = 0; mt < 4; mt++) {
      int rbase = (wr * 64 + mt * 16 + fm) * 64;
      af0[mt] = *(const bf16x8*)&As[cur][rbase + ak0];
      af1[mt] = *(const bf16x8*)&As[cur][rbase + ak1];
    }
    #pragma unroll
    for (int nt = 0; nt < 4; nt++) {
      int rbase = (wc * 64 + nt * 16 + fm) * 64;
      bf0[nt] = *(const bf16x8*)&Bs[cur][rbase + ak0];
      bf1[nt] = *(const bf16x8*)&Bs[cur][rbase + ak1];
    }
    #pragma unroll
    for (int mt = 0; mt < 4; mt++)
      #pragma unroll
      for (int nt = 0; nt < 4; nt++) {
        acc[mt][nt] = __builtin_amdgcn_mfma_f32_16x16x32_bf16(af0[mt], bf0[nt], acc[mt][nt], 0, 0, 0);
        acc[mt][nt] = __builtin_amdgcn_mfma_f32_16x16x32_bf16(af1[mt], bf1[nt], acc[mt][nt], 0, 0, 0);
      }
    __syncthreads();
    cur ^= 1;
  }
  // epilogue; wave's 64 cols = one head
  int colw = col0 + wc * 64;
  bool isK = isQ || (colw < 1024);
  int h = (isK ? colw : colw - 1024) >> 6;
  if (isK) {
    const float* scale = isQ ? qs : ks;
    float sv[4];
    #pragma unroll
    for (int nt = 0; nt < 4; nt++) sv[nt] = scale[nt * 16 + fm];
    if (isQ) {
      #pragma unroll
      for (int nt = 0; nt < 4; nt++) sv[nt] *= S8L_;
    }
    u16* Do = isQ ? Qn : Kb;
    #pragma unroll
    for (int mt = 0; mt < 4; mt++) {
      #pragma unroll
      for (int r = 0; r < 4; r++) {
        float ssp = 0.0f;
        #pragma unroll
        for (int nt = 0; nt < 4; nt++) ssp += acc[mt][nt][r] * acc[mt][nt][r];
        #pragma unroll
        for (int o = 1; o <= 8; o <<= 1) ssp += __shfl_xor(ssp, o, 64);
        float inv = 1.0f / fmaxf(sqrtf(ssp), 1e-12f);
        int m = row0 + wr * 64 + mt * 16 + fg4 + r;
        int b = m >> 11, n = m & 2047;
        size_t base;
        if (isQ) base = (((size_t)(b * H_ + h)) * N_ + n) * 64;
        else     base = (((size_t)(b * H_ + h)) * JP_ + (n + NN_)) * 64;
        #pragma unroll
        for (int nt = 0; nt < 4; nt++)
          Do[base + nt * 16 + fm] = f2b(acc[mt][nt][r] * inv * sv[nt]);
      }
    }
  } else {
    // V -> VTp directly (permuted): VTp[(bh*64 + d)*JP + c*64 + pos(jl)]
    #pragma unroll
    for (int mt = 0; mt < 4; mt++) {
      #pragma unroll
      for (int r = 0; r < 4; r++) {
        int m = row0 + wr * 64 + mt * 16 + fg4 + r;
        int b = m >> 11, n = m & 2047;
        int j = n + NN_;
        int c2 = j >> 6, jl = j & 63;
        int rem = jl & 31;
        int pos = (jl >> 5) * 32 + ((rem >> 2) & 3) * 8 + (rem >> 4) * 4 + (rem & 3);
        size_t hb = (size_t)(b * H_ + h) * 64;
        int off = c2 * 64 + pos;
        #pragma unroll
        for (int nt = 0; nt < 4; nt++)
          VTp[(hb + nt * 16 + fm) * JP_ + off] = f2b(acc[mt][nt][r]);
      }
    }
  }
}

// ---------------- MFMA GEMM MODE 1 (out-projection): 128x128 tile, fp32 out ------
__global__ __launch_bounds__(256) void gemm1_k(const u16* __restrict__ A,
                                               const u16* __restrict__ BT,
                                               float* __restrict__ C,
                                               int M, int Nc, int K) {
  __shared__ u16 As[2][128 * 64];
  __shared__ u16 Bs[2][128 * 64];
  int tid = threadIdx.x, wv = tid >> 6, lane = tid & 63;
  int fm = lane & 15, fg = lane >> 4;
  int fg4 = fg * 4;
  int wr = wv >> 1, wc = wv & 1;
  int nlin = (int)blockIdx.x + (int)gridDim.x * (int)blockIdx.y;
  int gx = (int)gridDim.x;
  int mm = nlin >> 3;
  int row0 = ((nlin & 7) * 4 + mm / gx) * 128;
  int col0 = (mm % gx) * 128;
  f32x4 acc[4][4] = {};
  int srow = lane >> 3;
  int skb = ((lane & 7) ^ srow) * 8;
  const u16* Ag = A + (size_t)(row0 + wv * 32 + srow) * K + skb;
  const u16* Bg = BT + (size_t)(col0 + wv * 32 + srow) * K + skb;
  int fr7 = fm & 7;
  int ak0 = (fg ^ fr7) * 8;
  int ak1 = ((fg + 4) ^ fr7) * 8;
  auto stageg = [&](int k0, int buf) {
    u16* AsW = As[buf] + (wv * 32) * 64;
    u16* BsW = Bs[buf] + (wv * 32) * 64;
    dma16(Ag + k0,                    AsW);
    dma16(Ag + (size_t)8 * K + k0,    AsW + 8 * 64);
    dma16(Ag + (size_t)16 * K + k0,   AsW + 16 * 64);
    dma16(Ag + (size_t)24 * K + k0,   AsW + 24 * 64);
    dma16(Bg + k0,                    BsW);
    dma16(Bg + (size_t)8 * K + k0,    BsW + 8 * 64);
    dma16(Bg + (size_t)16 * K + k0,   BsW + 16 * 64);
    dma16(Bg + (size_t)24 * K + k0,   BsW + 24 * 64);
  };
  stageg(0, 0);
  __syncthreads();
  int cur = 0;
  for (int k0 = 0; k0 < K; k0 += 64) {
    if (k0 + 64 < K) stageg(k0 + 64, cur ^ 1);
    bf16x8 af0[4], af1[4], bf0[4], bf1[4];
    #pragma unroll
    for (int mt = 0; mt < 4; mt++) {
      int rbase = (wr * 64 + mt * 16 + fm) * 64;
      af0[mt] = *(const bf16x8*)&As[cur][rbase + ak0];
      af1[mt] = *(const bf16x8*)&As[cur][rbase + ak1];
    }
    #pragma unroll
    for (int nt = 0; nt < 4; nt++) {
      int rbase = (wc * 64 + nt * 16 + fm) * 64;
      bf0[nt] = *(const bf16x8*)&Bs[cur][rbase + ak0];
      bf1[nt] = *(const bf16x8*)&Bs[cur][rbase + ak1];
    }
    #pragma unroll
    for (int mt = 0; mt < 4; mt++)
      #pragma unroll
      for (int nt = 0; nt < 4; nt++) {
        acc[mt][nt] = __builtin_amdgcn_mfma_f32_16x16x32_bf16(af0[mt], bf0[nt], acc[mt][nt], 0, 0, 0);
        acc[mt][nt] = __builtin_amdgcn_mfma_f32_16x16x32_bf16(af1[mt], bf1[nt], acc[mt][nt], 0, 0, 0);
      }
    __syncthreads();
    cur ^= 1;
  }
  int colw = col0 + wc * 64;
  #pragma unroll
  for (int mt = 0; mt < 4; mt++)
    #pragma unroll
    for (int r = 0; r < 4; r++) {
      int m = row0 + wr * 64 + mt * 16 + fg4 + r;
      #pragma unroll
      for (int nt = 0; nt < 4; nt++)
        C[(size_t)m * Nc + colw + nt * 16 + fm] = acc[mt][nt][r];
    }
}

// ---------------- MFMA flash attention, 64-row q-tiles, counted-vmcnt pipeline -----
// R10: R9 pipeline + FULL fence discipline (R9 raced: raw s_barrier is NOT a
//   compiler memory fence -- ds_reads/MFMAs can be scheduler-moved across it,
//   guide rule #18 / m152). Every sync point is now:
//     s_waitcnt (asm, memory clobber) -> sched_barrier(0) -> s_barrier -> sched_barrier(0)
//   and the end-of-iteration barrier is preceded by s_waitcnt lgkmcnt(0) +
//   sched_barrier(0) so this wave's ds_reads are retired to registers before any
//   wave can re-stage the buffers.
// Pipeline per chunk (K dbuf 16KB, V single 8KB, LDS 24KB -> 6 blocks/CU):
//   issue V(c), K(c+1)           [unconditional -> uniform FIFO]
//   vmcnt(4)+bar: waits only K(c) (issued last iter; latency hidden under prev compute)
//   QK^T + softmax               (V(c), K(c+1) in flight)
//   vmcnt(2)+bar: waits only V(c) (latency hidden under QK^T+softmax)
//   PV
//   lgkmcnt(0)+bar: LDS reads retired before re-staging
// Prologue ends with vmcnt(2)+pin: loop entered with exactly K(c0)x2 outstanding.
// One-past-end K prefetch reads next bh's rows (bh=31: lands in VTp) - never consumed.
__global__ __launch_bounds__(256, 6) void attn_k(const u16* __restrict__ Qn,
                                                 const u16* __restrict__ Kb,
                                                 const u16* __restrict__ VTp,
                                                 const float* __restrict__ qs,
                                                 const float* __restrict__ ks,
                                                 u16* __restrict__ partials) {
  __shared__ u16 Ks0[2][64 * 32], Ks1[2][64 * 32];  // K dbuf: rows j, d 0..31 / 32..63
  __shared__ u16 Vs0[64 * 32], Vs1[64 * 32];        // V^T: rows d, j-pos 0..31 / 32..63
  int tid = threadIdx.x;
  int wv = tid >> 6, lane = tid & 63;
  int fm = lane & 15, fg = lane >> 4;
  // ---- T1 bijective XCD remap ----
  int n = (int)blockIdx.x + NSEG_ * (int)blockIdx.y;   // hw linear id (x-major)
  int m = n >> 3;                                      // 0..335
  int bh = (n & 7) * 4 + m / NSEG_;                    // 4 bh per XCD
  int segid = m % NSEG_;                               // segment within bh
  int h = bh & 15;
  // segment decode (qt descending)
  int cum = 0, qt = 0, seg = 0;
  #pragma unroll 1
  for (int i = 0; i < 32; i++) {
    int t = 31 - i, s = (t + 9) >> 3;
    if (segid < cum + s) { qt = t; seg = segid - cum; break; }
    cum += s;
  }
  int q0 = qt * 64;
  int q = q0 + wv * 16 + fm;
  float slope = exp2f(-0.5f * (float)(h + 1));
  float prod = fabsf(qs[lane] * ks[lane]);
  #pragma unroll
  for (int o = 32; o; o >>= 1) prod = fmaxf(prod, __shfl_xor(prod, o, 64));
  float MbL = 8.0f * prod * LOG2E_;          // max-bound, in log2 domain
  float slopeL = slope * LOG2E_;
  const u16* qp = Qn + ((size_t)bh * N_ + q) * 64 + fg * 8;
  bf16x8 qf0 = *(const bf16x8*)(qp);        // d 0..31 slice
  bf16x8 qf1 = *(const bf16x8*)(qp + 32);   // d 32..63 slice
  f32x4 accO[4] = {};
  float lp = 0.0f;
  int lr = lane >> 2;                                  // staging row 0..15
  int kbs = ((lane & 3) ^ ((lane >> 3) & 3)) * 8;      // swizzled staging k-offset
  int fs = (fg ^ ((fm >> 1) & 3)) * 8;                 // swizzled frag offset
  const u16* KbBH = Kb + (size_t)bh * JP_ * 64;
  const u16* VTbh = VTp + (size_t)bh * 64 * JP_;
  int c0 = seg * 8;
  int c1 = min(c0 + 8, qt + 2);
  // running bias scalars (log2 domain): bias0 at (chunk start, nt=0, r=0)
  float bias0 = slopeL * (float)(c0 * 64 + fg * 4 - q - 2) - MbL;
  float sr1 = slopeL, sr2 = slopeL * 2.0f, sr3 = slopeL * 3.0f;
  float s16 = slopeL * 16.0f;
  float d64 = slopeL * 64.0f;
  // ---- prologue: stage K(c0) into buffer 0; settle FIFO to exactly these 2 ----
  {
    const u16* Kg = KbBH + (size_t)(c0 * 64 + wv * 16 + lr) * 64 + kbs;
    dma16(Kg,      Ks0[0] + wv * 512);
    dma16(Kg + 32, Ks1[0] + wv * 512);
  }
  asm volatile("s_waitcnt vmcnt(2)" ::: "memory");   // all earlier loads (Qn/qs/ks) retired
  __builtin_amdgcn_sched_barrier(0);
  int cur = 0;
  #pragma unroll 1
  for (int c = c0; c < c1; c++) {
    int jb = c * 64;
    // issue V(c), then K(c+1) into the other K buffer (unconditional)
    const u16* Vg = VTbh + (size_t)(wv * 16 + lr) * JP_ + jb + kbs;
    dma16(Vg,      Vs0 + wv * 512);
    dma16(Vg + 32, Vs1 + wv * 512);
    const u16* Kg = KbBH + (size_t)(jb + 64 + wv * 16 + lr) * 64 + kbs;
    dma16(Kg,      Ks0[cur ^ 1] + wv * 512);
    dma16(Kg + 32, Ks1[cur ^ 1] + wv * 512);
    // wait K(c) only (leaves V(c), K(c+1) in flight); fenced barrier
    asm volatile("s_waitcnt vmcnt(4)" ::: "memory");
    __builtin_amdgcn_sched_barrier(0);
    __builtin_amdgcn_s_barrier();
    __builtin_amdgcn_sched_barrier(0);
    // S^T = K Q^T  (Qn pre-scaled by 8*log2e)
    f32x4 accS[4] = {};
    #pragma unroll
    for (int nt = 0; nt < 4; nt++) {
      bf16x8 kf0 = *(const bf16x8*)&Ks0[cur][(nt * 16 + fm) * 32 + fs];
      accS[nt] = __builtin_amdgcn_mfma_f32_16x16x32_bf16(kf0, qf0, accS[nt], 0, 0, 0);
      bf16x8 kf1 = *(const bf16x8*)&Ks1[cur][(nt * 16 + fm) * 32 + fs];
      accS[nt] = __builtin_amdgcn_mfma_f32_16x16x32_bf16(kf1, qf1, accS[nt], 0, 0, 0);
    }
    // softmax in-register; pack P^T B-frags immediately
    union { bf16x8 v; u32 u[4]; } P0, P1;
    float lps = 0.0f;
    float bnt = bias0;
    if (c < qt) {
      #pragma unroll
      for (int nt = 0; nt < 4; nt++) {
        float e0 = __builtin_amdgcn_exp2f(accS[nt][0] + bnt);
        float e1 = __builtin_amdgcn_exp2f((accS[nt][1] + sr1) + bnt);
        float e2 = __builtin_amdgcn_exp2f((accS[nt][2] + sr2) + bnt);
        float e3 = __builtin_amdgcn_exp2f((accS[nt][3] + sr3) + bnt);
        u32 w0 = pk2(e0, e1);
        u32 w1 = pk2(e2, e3);
        lps += (e0 + e1) + (e2 + e3);
        if (nt < 2) { P0.u[nt * 2] = w0; P0.u[nt * 2 + 1] = w1; }
        else        { P1.u[(nt - 2) * 2] = w0; P1.u[(nt - 2) * 2 + 1] = w1; }
        bnt += s16;
      }
    } else {
      // diagonal chunk: per-element causal mask (idx <= thr  <=>  jj <= q+2)
      int thr = q + 2 - jb;
      #pragma unroll
      for (int nt = 0; nt < 4; nt++) {
        int ib = nt * 16 + fg * 4;
        float e0 = __builtin_amdgcn_exp2f(accS[nt][0] + bnt);
        float e1 = __builtin_amdgcn_exp2f((accS[nt][1] + sr1) + bnt);
        float e2 = __builtin_amdgcn_exp2f((accS[nt][2] + sr2) + bnt);
        float e3 = __builtin_amdgcn_exp2f((accS[nt][3] + sr3) + bnt);
        e0 = (ib + 0 <= thr) ? e0 : 0.0f;
        e1 = (ib + 1 <= thr) ? e1 : 0.0f;
        e2 = (ib + 2 <= thr) ? e2 : 0.0f;
        e3 = (ib + 3 <= thr) ? e3 : 0.0f;
        u32 w0 = pk2(e0, e1);
        u32 w1 = pk2(e2, e3);
        lps += (e0 + e1) + (e2 + e3);
        if (nt < 2) { P0.u[nt * 2] = w0; P0.u[nt * 2 + 1] = w1; }
        else        { P1.u[(nt - 2) * 2] = w0; P1.u[(nt - 2) * 2 + 1] = w1; }
        bnt += s16;
      }
    }
    lp += lps;
    bias0 += d64;
    // wait V(c) only (leaves K(c+1) in flight); fenced barrier
    asm volatile("s_waitcnt vmcnt(2)" ::: "memory");
    __builtin_amdgcn_sched_barrier(0);
    __builtin_amdgcn_s_barrier();
    __builtin_amdgcn_sched_barrier(0);
    // O^T += V^T P^T
    #pragma unroll
    for (int nt = 0; nt < 4; nt++) {
      bf16x8 vf0 = *(const bf16x8*)&Vs0[(nt * 16 + fm) * 32 + fs];
      accO[nt] = __builtin_amdgcn_mfma_f32_16x16x32_bf16(vf0, P0.v, accO[nt], 0, 0, 0);
      bf16x8 vf1 = *(const bf16x8*)&Vs1[(nt * 16 + fm) * 32 + fs];
      accO[nt] = __builtin_amdgcn_mfma_f32_16x16x32_bf16(vf1, P1.v, accO[nt], 0, 0, 0);
    }
    // retire this wave's LDS reads, then barrier: no wave re-stages Vs/Ks[cur]
    // until every wave's reads have landed in registers.
    asm volatile("s_waitcnt lgkmcnt(0)" ::: "memory");
    __builtin_amdgcn_sched_barrier(0);
    __builtin_amdgcn_s_barrier();
    __builtin_amdgcn_sched_barrier(0);
    cur ^= 1;
  }
  lp += __shfl_xor(lp, 16, 64);
  lp += __shfl_xor(lp, 32, 64);
  // slot: [q 64][d 64] bf16 + l fp32[64]
  u16* P = partials + ((size_t)bh * NSEG_ + segid) * 4224;
  int sq = wv * 16 + fm;
  #pragma unroll
  for (int nt = 0; nt < 4; nt++) {
    uint2 ow;
    ow.x = pk2(accO[nt][0], accO[nt][1]);
    ow.y = pk2(accO[nt][2], accO[nt][3]);
    *(uint2*)(P + sq * 64 + nt * 16 + fg * 4) = ow;
  }
  if (fg == 0) *(float*)(P + 4096 + 2 * sq) = lp;
}

// ---------------- combine partials -> AO (b,n,h,d), 64-row tiles ----------------
__global__ __launch_bounds__(256) void comb_k(const u16* __restrict__ partials,
                                              u16* __restrict__ AO) {
  int qt = blockIdx.x, bh = blockIdx.y, b = bh >> 4, h = bh & 15;
  int t = threadIdx.x, q = t >> 2, dq = (t & 3) * 16;
  int s = (qt + 9) >> 3;
  int cum = 0;
  for (int tt = qt + 1; tt < 32; tt++) cum += (tt + 9) >> 3;
  float acc[16] = {};
  float lsum = 0.0f;
  for (int k = 0; k < s; k++) {
    const u16* P = partials + ((size_t)bh * NSEG_ + cum + k) * 4224;
    uint4 a = *(const uint4*)(P + q * 64 + dq);
    uint4 bq = *(const uint4*)(P + q * 64 + dq + 8);
    float tmp[8];
    unp8(a, tmp);
    #pragma unroll
    for (int e = 0; e < 8; e++) acc[e] += tmp[e];
    unp8(bq, tmp);
    #pragma unroll
    for (int e = 0; e < 8; e++) acc[8 + e] += tmp[e];
    lsum += *(const float*)(P + 4096 + 2 * q);
  }
  float linv = 1.0f / lsum;
  int n = qt * 64 + q;
  u16* dst = AO + (((size_t)(b * N_ + n)) * H_ + h) * 64 + dq;
  u16 ov[16] __attribute__((aligned(16)));
  #pragma unroll
  for (int e = 0; e < 16; e++) ov[e] = f2b(acc[e] * linv);
  *(uint4*)dst = ((uint4*)ov)[0];
  *(uint4*)(dst + 8) = ((uint4*)ov)[1];
}

// ---------------- launch ----------------
extern "C" void kernel_launch(void* const* d_in, const int* in_sizes, int n_in,
                              void* d_out, int out_size, void* d_ws, size_t ws_size,
                              hipStream_t stream) {
  const float* x    = (const float*)d_in[0];
  const float* ng   = (const float*)d_in[1];
  const float* nb   = (const float*)d_in[2];
  const float* Wq   = (const float*)d_in[3];
  const float* Wkv  = (const float*)d_in[4];
  const float* qs   = (const float*)d_in[5];
  const float* ks   = (const float*)d_in[6];
  const float* nkv  = (const float*)d_in[7];
  const float* Wout = (const float*)d_in[8];
  float* out = (float*)d_out;
  char* ws = (char*)d_ws;

  // layout (bytes):
  u16* xn    = (u16*)(ws + 0);            // 8,388,608 (AO reuses after Q-GEMM)
  u16* WoutT = (u16*)(ws + 8388608);      // 2,097,152
  u16* Qn    = (u16*)(ws + 10485760);     // 8,388,608
  u16* Kb    = (u16*)(ws + 18874368);     // 8,650,752 (JP stride)
  u16* VTp   = (u16*)(ws + 27525120);     // 8,650,752
  // overlay region @36175872 (dead by attn time):
  u16* xbf   = (u16*)(ws + 36175872);     // 8,388,608  (dead after KV-GEMM)
  u16* WqT   = (u16*)(ws + 44564480);     // 2,097,152  (dead after Q-GEMM)
  u16* WkvT  = (u16*)(ws + 46661632);     // 4,194,304  (dead after KV-GEMM)
  u16* parts = xbf;                       // 32*84*8448 = 22,708,224 (fits overlay)
  u16* AO    = xn;

  prep_k<<<dim3(259, 32), 256, 0, stream>>>(x, ng, nb, Wq, Wkv, Wout, nkv, ks,
                                            xn, xbf, WqT, WkvT, WoutT, Kb, VTp);
  gemmqkv_k<<<768, 256, 0, stream>>>(xn, WqT, xbf, WkvT, Qn, Kb, VTp, qs, ks);
  attn_k<<<dim3(NSEG_, 32), 256, 0, stream>>>(Qn, Kb, VTp, qs, ks, parts);
  comb_k<<<dim3(32, 32), 256, 0, stream>>>(parts, AO);
  gemm1_k<<<dim3(8, 32), 256, 0, stream>>>(AO, WoutT, out, M_, 1024, 1024);
}

// Round 12
// 210.519 us; speedup vs baseline: 1.0199x; 1.0199x over previous
//
#include <hip/hip_runtime.h>
#include <hip/hip_bf16.h>
#include <stdint.h>

// Problem constants
#define H_    16
#define N_    2048
#define DIM_  1024
#define DH_   64
#define NN_   2
#define J_    2050     // N + NNULL
#define JP_   2112     // 33*64, padded j (tails zeroed in prep)
#define B_    2
#define M_    4096     // B * N
#define NSEG_ 84       // sum over qt of ceil((qt+2)/8)  (64-row q-tiles)

#define S8L_  11.541560327111707f   // 8 * log2(e), folded into Qn at Q-GEMM epilogue
#define LOG2E_ 1.4426950408889634f

typedef unsigned short u16;
typedef unsigned int u32;
typedef short bf16x8 __attribute__((ext_vector_type(8)));
typedef float f32x4 __attribute__((ext_vector_type(4)));

__device__ __forceinline__ u16 f2b(float f) {
  union { float f; unsigned int i; } v; v.f = f;
  unsigned int r = v.i + 0x7fffu + ((v.i >> 16) & 1u);   // RNE
  return (u16)(r >> 16);
}
__device__ __forceinline__ float lo2f(u32 u) {
  union { u32 i; float f; } v; v.i = u << 16; return v.f;
}
__device__ __forceinline__ float hi2f(u32 u) {
  union { u32 i; float f; } v; v.i = u & 0xffff0000u; return v.f;
}
__device__ __forceinline__ void unp8(const uint4 u, float* d) {
  d[0] = lo2f(u.x); d[1] = hi2f(u.x); d[2] = lo2f(u.y); d[3] = hi2f(u.y);
  d[4] = lo2f(u.z); d[5] = hi2f(u.z); d[6] = lo2f(u.w); d[7] = hi2f(u.w);
}
// packed fp32x2 -> bf16x2 (single v_cvt_pk_bf16_f32)
__device__ __forceinline__ u32 pk2(float a, float b) {
  union { __hip_bfloat162 h; u32 u; } x;
  x.h = __float22bfloat162_rn(make_float2(a, b));
  return x.u;
}
// async global->LDS DMA, 16B/lane; LDS dest = wave-uniform base + lane*16
__device__ __forceinline__ void dma16(const u16* g, u16* l) {
  __builtin_amdgcn_global_load_lds(
      (const __attribute__((address_space(1))) u32*)(const void*)g,
      (__attribute__((address_space(3))) u32*)(void*)l, 16, 0, 0);
}

// ---------------- fused prep kernel ----------------
// bx <  128 : transpose+cast Wq/Wkv/Wout (fp32 RxC -> bf16 CxR)
// bx in [128,256): LayerNorm row (bx-128)*32+by -> xn, and bf16 cast -> xbf
// bx == 256 : null-kv rows j<2 -> Kb (l2norm*ks) and VTp (pos=j at c=0)
// bx == 257 : zero Kb rows j in [2048,2112) (j=2048,2049 overwritten by KV-GEMM after)
// bx == 258 : zero VTp chunk c=32 (pos 0,1 overwritten by KV-GEMM after)
__global__ __launch_bounds__(256) void prep_k(const float* __restrict__ x,
                                              const float* __restrict__ g,
                                              const float* __restrict__ bb,
                                              const float* __restrict__ Wq,
                                              const float* __restrict__ Wkv,
                                              const float* __restrict__ Wout,
                                              const float* __restrict__ nkv,
                                              const float* __restrict__ ks,
                                              u16* __restrict__ xn,
                                              u16* __restrict__ xbf,
                                              u16* __restrict__ WqT,
                                              u16* __restrict__ WkvT,
                                              u16* __restrict__ WoutT,
                                              u16* __restrict__ Kb,
                                              u16* __restrict__ VTp) {
  __shared__ float tile[32][33];
  __shared__ float red[8];
  int bx = blockIdx.x, by = blockIdx.y;
  int t = threadIdx.x;
  if (bx < 128) {
    // ---- weight transpose+cast ----
    const float* in; u16* out; int C; int cx;
    if (bx < 32)      { in = Wq;   out = WqT;   C = 1024; cx = bx; }
    else if (bx < 96) { in = Wkv;  out = WkvT;  C = 2048; cx = bx - 32; }
    else              { in = Wout; out = WoutT; C = 1024; cx = bx - 96; }
    const int R = 1024;
    int tx = t & 31, ty = t >> 5;   // 32 x 8
    int c0 = cx * 32, r0 = by * 32;
    #pragma unroll
    for (int i = 0; i < 32; i += 8)
      tile[ty + i][tx] = in[(size_t)(r0 + ty + i) * C + c0 + tx];
    __syncthreads();
    #pragma unroll
    for (int i = 0; i < 32; i += 8)
      out[(size_t)(c0 + ty + i) * R + r0 + tx] = f2b(tile[tx][ty + i]);
  } else if (bx < 256) {
    // ---- LayerNorm ----
    int row = (bx - 128) * 32 + by;
    float4 rw = *(const float4*)(x + (size_t)row * DIM_ + t * 4);
    float v0 = rw.x, v1 = rw.y, v2 = rw.z, v3 = rw.w;
    uint2 cw;
    cw.x = pk2(v0, v1);
    cw.y = pk2(v2, v3);
    *(uint2*)(xbf + (size_t)row * DIM_ + t * 4) = cw;
    float s = v0 + v1 + v2 + v3;
    float ss = v0 * v0 + v1 * v1 + v2 * v2 + v3 * v3;
    #pragma unroll
    for (int o = 32; o; o >>= 1) { s += __shfl_xor(s, o, 64); ss += __shfl_xor(ss, o, 64); }
    int lane = t & 63, w = t >> 6;
    if (lane == 0) { red[w] = s; red[4 + w] = ss; }
    __syncthreads();
    float S = red[0] + red[1] + red[2] + red[3];
    float SS = red[4] + red[5] + red[6] + red[7];
    float mu = S * (1.0f / DIM_);
    float var = SS * (1.0f / DIM_) - mu * mu;
    float rs = rsqrtf(var + 1e-5f);
    float4 gv = *(const float4*)(g + t * 4);
    float4 bv = *(const float4*)(bb + t * 4);
    uint2 ow;
    ow.x = pk2((v0 - mu) * rs * gv.x + bv.x, (v1 - mu) * rs * gv.y + bv.y);
    ow.y = pk2((v2 - mu) * rs * gv.z + bv.z, (v3 - mu) * rs * gv.w + bv.w);
    *(uint2*)(xn + (size_t)row * DIM_ + t * 4) = ow;
  } else if (bx == 256) {
    // ---- null kv: j = 0,1 ----
    int bh = by, h = bh & 15;
    if (t < 128) {
      int j = t >> 6, d = t & 63;
      float kv = nkv[(size_t)(h * 4 + 2 * j) * 64 + d];
      float vv = nkv[(size_t)(h * 4 + 2 * j + 1) * 64 + d];
      float ssp = kv * kv;
      #pragma unroll
      for (int o = 32; o; o >>= 1) ssp += __shfl_xor(ssp, o, 64);
      float inv = 1.0f / fmaxf(sqrtf(ssp), 1e-12f);
      Kb[((size_t)bh * JP_ + j) * 64 + d] = f2b(kv * inv * ks[d]);
      VTp[((size_t)bh * 64 + d) * JP_ + j] = f2b(vv);
    }
  } else if (bx == 257) {
    // ---- zero Kb rows j in [2048, 2112) ----
    int bh = by;
    uint4 z = {0, 0, 0, 0};
    u16* dst = Kb + ((size_t)bh * JP_ + 2048) * 64 + t * 16;
    ((uint4*)dst)[0] = z;
    ((uint4*)dst)[1] = z;
  } else {
    // ---- zero VTp chunk c=32 ----
    int bh = by;
    uint4 z = {0, 0, 0, 0};
    int d = t >> 2, p0 = (t & 3) * 16;
    u16* dst = VTp + ((size_t)bh * 64 + d) * JP_ + 2048 + p0;
    ((uint4*)dst)[0] = z;
    ((uint4*)dst)[1] = z;
  }
}

// fenced sync-point helpers (R10-proven pattern: wait -> pin -> barrier -> pin)
#define FENCED_WAIT_BAR(WAITSTR)                     \
  asm volatile(WAITSTR ::: "memory");                \
  __builtin_amdgcn_sched_barrier(0);                 \
  __builtin_amdgcn_s_barrier();                      \
  __builtin_amdgcn_sched_barrier(0);

// ---------------- fused Q + KV GEMM, 128x128 tiles, BK=64, dbuf ----------------
// R11: counted-vmcnt K-loop (T4, R10 attn pattern ported). The old __syncthreads
//   drained vmcnt(0) INCLUDING the just-issued prefetch -> dbuf defeated, 59us at
//   MfmaUtil 16 / occupancy 14 (2 blocks/CU can't hide the serial drain). Now:
//   stage(next) -> vmcnt(8) (retires all but the 8 newest = the prefetch; by FIFO
//   order buf[cur] and any earlier/hoisted loads are retired) -> fenced barrier ->
//   compute -> lgkmcnt(0) + fenced barrier (ds_reads retired before re-stage).
//   Last iter: no prefetch -> vmcnt(0).
// nlin<256 -> Q (xn @ WqT, l2norm*qs*8log2e -> Qn); else -> KV (xbf @ WkvT;
// K cols: l2norm*ks -> Kb; V cols -> VTp permuted). 256%8==0 keeps XCD remaps bijective.
// pos(jl) = (jl>>5)*32 + ((jl>>2)&3)*8 + ((jl>>4)&1)*4 + (jl&3)   [pi inverse]
__global__ __launch_bounds__(256) void gemmqkv_k(const u16* __restrict__ xn,
                                                 const u16* __restrict__ WqT,
                                                 const u16* __restrict__ xbf,
                                                 const u16* __restrict__ WkvT,
                                                 u16* __restrict__ Qn,
                                                 u16* __restrict__ Kb,
                                                 u16* __restrict__ VTp,
                                                 const float* __restrict__ qs,
                                                 const float* __restrict__ ks) {
  __shared__ u16 As[2][128 * 64];   // 32 KB
  __shared__ u16 Bs[2][128 * 64];   // 32 KB
  const int K = 1024;
  int tid = threadIdx.x, wv = tid >> 6, lane = tid & 63;
  int fm = lane & 15, fg = lane >> 4;
  int fg4 = fg * 4;
  int wr = wv >> 1, wc = wv & 1;           // 2x2 wave grid
  int nlin = (int)blockIdx.x;
  bool isQ = nlin < 256;
  const u16* A;
  const u16* BT;
  int gx, local;
  if (isQ) { A = xn;  BT = WqT;  gx = 8;  local = nlin; }
  else     { A = xbf; BT = WkvT; gx = 16; local = nlin - 256; }
  // bijective XCD y-chunk remap within the sub-problem (local%8 == hw nlin%8)
  int mm = local >> 3;
  int row0 = ((local & 7) * 4 + mm / gx) * 128;
  int col0 = (mm % gx) * 128;
  f32x4 acc[4][4] = {};
  int srow = lane >> 3;                 // 0..7
  int skb = ((lane & 7) ^ srow) * 8;    // swizzled global k-offset (u16)
  const u16* Ag = A + (size_t)(row0 + wv * 32 + srow) * K + skb;
  const u16* Bg = BT + (size_t)(col0 + wv * 32 + srow) * K + skb;
  int fr7 = fm & 7;
  int ak0 = (fg ^ fr7) * 8;
  int ak1 = ((fg + 4) ^ fr7) * 8;
  auto stageg = [&](int k0, int buf) {
    u16* AsW = As[buf] + (wv * 32) * 64;
    u16* BsW = Bs[buf] + (wv * 32) * 64;
    dma16(Ag + k0,                    AsW);
    dma16(Ag + (size_t)8 * K + k0,    AsW + 8 * 64);
    dma16(Ag + (size_t)16 * K + k0,   AsW + 16 * 64);
    dma16(Ag + (size_t)24 * K + k0,   AsW + 24 * 64);
    dma16(Bg + k0,                    BsW);
    dma16(Bg + (size_t)8 * K + k0,    BsW + 8 * 64);
    dma16(Bg + (size_t)16 * K + k0,   BsW + 16 * 64);
    dma16(Bg + (size_t)24 * K + k0,   BsW + 24 * 64);
  };
  stageg(0, 0);
  __builtin_amdgcn_sched_barrier(0);
  int cur = 0;
  #pragma unroll 1
  for (int k0 = 0; k0 < K; k0 += 64) {
    bool hasNext = (k0 + 64 < K);
    if (hasNext) stageg(k0 + 64, cur ^ 1);
    __builtin_amdgcn_sched_barrier(0);
    if (hasNext) {
      FENCED_WAIT_BAR("s_waitcnt vmcnt(8)")
    } else {
      FENCED_WAIT_BAR("s_waitcnt vmcnt(0)")
    }
    bf16x8 af0[4], af1[4], bf0[4], bf1[4];
    #pragma unroll
    for (int mt = 0; mt < 4; mt++) {
      int rbase = (wr * 64 + mt * 16 + fm) * 64;
      af0[mt] = *(const bf16x8*)&As[cur][rbase + ak0];
      af1[mt] = *(const bf16x8*)&As[cur][rbase + ak1];
    }
    #pragma unroll
    for (int nt = 0; nt < 4; nt++) {
      int rbase = (wc * 64 + nt * 16 + fm) * 64;
      bf0[nt] = *(const bf16x8*)&Bs[cur][rbase + ak0];
      bf1[nt] = *(const bf16x8*)&Bs[cur][rbase + ak1];
    }
    #pragma unroll
    for (int mt = 0; mt < 4; mt++)
      #pragma unroll
      for (int nt = 0; nt < 4; nt++) {
        acc[mt][nt] = __builtin_amdgcn_mfma_f32_16x16x32_bf16(af0[mt], bf0[nt], acc[mt][nt], 0, 0, 0);
        acc[mt][nt] = __builtin_amdgcn_mfma_f32_16x16x32_bf16(af1[mt], bf1[nt], acc[mt][nt], 0, 0, 0);
      }
    // ds_reads retired to registers before any wave re-stages buf[cur^1]
    FENCED_WAIT_BAR("s_waitcnt lgkmcnt(0)")
    cur ^= 1;
  }
  // epilogue; wave's 64 cols = one head
  int colw = col0 + wc * 64;
  bool isK = isQ || (colw < 1024);
  int h = (isK ? colw : colw - 1024) >> 6;
  if (isK) {
    const float* scale = isQ ? qs : ks;
    float sv[4];
    #pragma unroll
    for (int nt = 0; nt < 4; nt++) sv[nt] = scale[nt * 16 + fm];
    if (isQ) {
      #pragma unroll
      for (int nt = 0; nt < 4; nt++) sv[nt] *= S8L_;
    }
    u16* Do = isQ ? Qn : Kb;
    #pragma unroll
    for (int mt = 0; mt < 4; mt++) {
      #pragma unroll
      for (int r = 0; r < 4; r++) {
        float ssp = 0.0f;
        #pragma unroll
        for (int nt = 0; nt < 4; nt++) ssp += acc[mt][nt][r] * acc[mt][nt][r];
        #pragma unroll
        for (int o = 1; o <= 8; o <<= 1) ssp += __shfl_xor(ssp, o, 64);
        float inv = 1.0f / fmaxf(sqrtf(ssp), 1e-12f);
        int m = row0 + wr * 64 + mt * 16 + fg4 + r;
        int b = m >> 11, n = m & 2047;
        size_t base;
        if (isQ) base = (((size_t)(b * H_ + h)) * N_ + n) * 64;
        else     base = (((size_t)(b * H_ + h)) * JP_ + (n + NN_)) * 64;
        #pragma unroll
        for (int nt = 0; nt < 4; nt++)
          Do[base + nt * 16 + fm] = f2b(acc[mt][nt][r] * inv * sv[nt]);
      }
    }
  } else {
    // V -> VTp directly (permuted): VTp[(bh*64 + d)*JP + c*64 + pos(jl)]
    #pragma unroll
    for (int mt = 0; mt < 4; mt++) {
      #pragma unroll
      for (int r = 0; r < 4; r++) {
        int m = row0 + wr * 64 + mt * 16 + fg4 + r;
        int b = m >> 11, n = m & 2047;
        int j = n + NN_;
        int c2 = j >> 6, jl = j & 63;
        int rem = jl & 31;
        int pos = (jl >> 5) * 32 + ((rem >> 2) & 3) * 8 + (rem >> 4) * 4 + (rem & 3);
        size_t hb = (size_t)(b * H_ + h) * 64;
        int off = c2 * 64 + pos;
        #pragma unroll
        for (int nt = 0; nt < 4; nt++)
          VTp[(hb + nt * 16 + fm) * JP_ + off] = f2b(acc[mt][nt][r]);
      }
    }
  }
}

// ---------------- MFMA GEMM MODE 1 (out-projection): 128x128 tile, fp32 out ------
// R11: same counted-vmcnt K-loop (grid 256 = 1 block/CU -> intra-block pipelining
// is the only latency hiding available here).
__global__ __launch_bounds__(256) void gemm1_k(const u16* __restrict__ A,
                                               const u16* __restrict__ BT,
                                               float* __restrict__ C,
                                               int M, int Nc, int K) {
  __shared__ u16 As[2][128 * 64];
  __shared__ u16 Bs[2][128 * 64];
  int tid = threadIdx.x, wv = tid >> 6, lane = tid & 63;
  int fm = lane & 15, fg = lane >> 4;
  int fg4 = fg * 4;
  int wr = wv >> 1, wc = wv & 1;
  int nlin = (int)blockIdx.x + (int)gridDim.x * (int)blockIdx.y;
  int gx = (int)gridDim.x;
  int mm = nlin >> 3;
  int row0 = ((nlin & 7) * 4 + mm / gx) * 128;
  int col0 = (mm % gx) * 128;
  f32x4 acc[4][4] = {};
  int srow = lane >> 3;
  int skb = ((lane & 7) ^ srow) * 8;
  const u16* Ag = A + (size_t)(row0 + wv * 32 + srow) * K + skb;
  const u16* Bg = BT + (size_t)(col0 + wv * 32 + srow) * K + skb;
  int fr7 = fm & 7;
  int ak0 = (fg ^ fr7) * 8;
  int ak1 = ((fg + 4) ^ fr7) * 8;
  auto stageg = [&](int k0, int buf) {
    u16* AsW = As[buf] + (wv * 32) * 64;
    u16* BsW = Bs[buf] + (wv * 32) * 64;
    dma16(Ag + k0,                    AsW);
    dma16(Ag + (size_t)8 * K + k0,    AsW + 8 * 64);
    dma16(Ag + (size_t)16 * K + k0,   AsW + 16 * 64);
    dma16(Ag + (size_t)24 * K + k0,   AsW + 24 * 64);
    dma16(Bg + k0,                    BsW);
    dma16(Bg + (size_t)8 * K + k0,    BsW + 8 * 64);
    dma16(Bg + (size_t)16 * K + k0,   BsW + 16 * 64);
    dma16(Bg + (size_t)24 * K + k0,   BsW + 24 * 64);
  };
  stageg(0, 0);
  __builtin_amdgcn_sched_barrier(0);
  int cur = 0;
  #pragma unroll 1
  for (int k0 = 0; k0 < K; k0 += 64) {
    bool hasNext = (k0 + 64 < K);
    if (hasNext) stageg(k0 + 64, cur ^ 1);
    __builtin_amdgcn_sched_barrier(0);
    if (hasNext) {
      FENCED_WAIT_BAR("s_waitcnt vmcnt(8)")
    } else {
      FENCED_WAIT_BAR("s_waitcnt vmcnt(0)")
    }
    bf16x8 af0[4], af1[4], bf0[4], bf1[4];
    #pragma unroll
    for (int mt = 0; mt < 4; mt++) {
      int rbase = (wr * 64 + mt * 16 + fm) * 64;
      af0[mt] = *(const bf16x8*)&As[cur][rbase + ak0];
      af1[mt] = *(const bf16x8*)&As[cur][rbase + ak1];
    }
    #pragma unroll
    for (int nt = 0; nt < 4; nt++) {
      int rbase = (wc * 64 + nt * 16 + fm) * 64;
      bf0[nt] = *(const bf16x8*)&Bs[cur][rbase + ak0];
      bf1[nt] = *(const bf16x8*)&Bs[cur][rbase + ak1];
    }
    #pragma unroll
    for (int mt = 0; mt < 4; mt++)
      #pragma unroll
      for (int nt = 0; nt < 4; nt++) {
        acc[mt][nt] = __builtin_amdgcn_mfma_f32_16x16x32_bf16(af0[mt], bf0[nt], acc[mt][nt], 0, 0, 0);
        acc[mt][nt] = __builtin_amdgcn_mfma_f32_16x16x32_bf16(af1[mt], bf1[nt], acc[mt][nt], 0, 0, 0);
      }
    FENCED_WAIT_BAR("s_waitcnt lgkmcnt(0)")
    cur ^= 1;
  }
  int colw = col0 + wc * 64;
  #pragma unroll
  for (int mt = 0; mt < 4; mt++)
    #pragma unroll
    for (int r = 0; r < 4; r++) {
      int m = row0 + wr * 64 + mt * 16 + fg4 + r;
      #pragma unroll
      for (int nt = 0; nt < 4; nt++)
        C[(size_t)m * Nc + colw + nt * 16 + fm] = acc[mt][nt][r];
    }
}

// ---------------- MFMA flash attention, 64-row q-tiles, counted-vmcnt pipeline -----
// R10 version unchanged (race-free fenced counted-vmcnt; dropped out of top-5).
__global__ __launch_bounds__(256, 6) void attn_k(const u16* __restrict__ Qn,
                                                 const u16* __restrict__ Kb,
                                                 const u16* __restrict__ VTp,
                                                 const float* __restrict__ qs,
                                                 const float* __restrict__ ks,
                                                 u16* __restrict__ partials) {
  __shared__ u16 Ks0[2][64 * 32], Ks1[2][64 * 32];  // K dbuf: rows j, d 0..31 / 32..63
  __shared__ u16 Vs0[64 * 32], Vs1[64 * 32];        // V^T: rows d, j-pos 0..31 / 32..63
  int tid = threadIdx.x;
  int wv = tid >> 6, lane = tid & 63;
  int fm = lane & 15, fg = lane >> 4;
  // ---- T1 bijective XCD remap ----
  int n = (int)blockIdx.x + NSEG_ * (int)blockIdx.y;   // hw linear id (x-major)
  int m = n >> 3;                                      // 0..335
  int bh = (n & 7) * 4 + m / NSEG_;                    // 4 bh per XCD
  int segid = m % NSEG_;                               // segment within bh
  int h = bh & 15;
  // segment decode (qt descending)
  int cum = 0, qt = 0, seg = 0;
  #pragma unroll 1
  for (int i = 0; i < 32; i++) {
    int t = 31 - i, s = (t + 9) >> 3;
    if (segid < cum + s) { qt = t; seg = segid - cum; break; }
    cum += s;
  }
  int q0 = qt * 64;
  int q = q0 + wv * 16 + fm;
  float slope = exp2f(-0.5f * (float)(h + 1));
  float prod = fabsf(qs[lane] * ks[lane]);
  #pragma unroll
  for (int o = 32; o; o >>= 1) prod = fmaxf(prod, __shfl_xor(prod, o, 64));
  float MbL = 8.0f * prod * LOG2E_;          // max-bound, in log2 domain
  float slopeL = slope * LOG2E_;
  const u16* qp = Qn + ((size_t)bh * N_ + q) * 64 + fg * 8;
  bf16x8 qf0 = *(const bf16x8*)(qp);        // d 0..31 slice
  bf16x8 qf1 = *(const bf16x8*)(qp + 32);   // d 32..63 slice
  f32x4 accO[4] = {};
  float lp = 0.0f;
  int lr = lane >> 2;                                  // staging row 0..15
  int kbs = ((lane & 3) ^ ((lane >> 3) & 3)) * 8;      // swizzled staging k-offset
  int fs = (fg ^ ((fm >> 1) & 3)) * 8;                 // swizzled frag offset
  const u16* KbBH = Kb + (size_t)bh * JP_ * 64;
  const u16* VTbh = VTp + (size_t)bh * 64 * JP_;
  int c0 = seg * 8;
  int c1 = min(c0 + 8, qt + 2);
  // running bias scalars (log2 domain): bias0 at (chunk start, nt=0, r=0)
  float bias0 = slopeL * (float)(c0 * 64 + fg * 4 - q - 2) - MbL;
  float sr1 = slopeL, sr2 = slopeL * 2.0f, sr3 = slopeL * 3.0f;
  float s16 = slopeL * 16.0f;
  float d64 = slopeL * 64.0f;
  // ---- prologue: stage K(c0) into buffer 0; settle FIFO to exactly these 2 ----
  {
    const u16* Kg = KbBH + (size_t)(c0 * 64 + wv * 16 + lr) * 64 + kbs;
    dma16(Kg,      Ks0[0] + wv * 512);
    dma16(Kg + 32, Ks1[0] + wv * 512);
  }
  asm volatile("s_waitcnt vmcnt(2)" ::: "memory");   // all earlier loads (Qn/qs/ks) retired
  __builtin_amdgcn_sched_barrier(0);
  int cur = 0;
  #pragma unroll 1
  for (int c = c0; c < c1; c++) {
    int jb = c * 64;
    // issue V(c), then K(c+1) into the other K buffer (unconditional)
    const u16* Vg = VTbh + (size_t)(wv * 16 + lr) * JP_ + jb + kbs;
    dma16(Vg,      Vs0 + wv * 512);
    dma16(Vg + 32, Vs1 + wv * 512);
    const u16* Kg = KbBH + (size_t)(jb + 64 + wv * 16 + lr) * 64 + kbs;
    dma16(Kg,      Ks0[cur ^ 1] + wv * 512);
    dma16(Kg + 32, Ks1[cur ^ 1] + wv * 512);
    // wait K(c) only (leaves V(c), K(c+1) in flight); fenced barrier
    FENCED_WAIT_BAR("s_waitcnt vmcnt(4)")
    // S^T = K Q^T  (Qn pre-scaled by 8*log2e)
    f32x4 accS[4] = {};
    #pragma unroll
    for (int nt = 0; nt < 4; nt++) {
      bf16x8 kf0 = *(const bf16x8*)&Ks0[cur][(nt * 16 + fm) * 32 + fs];
      accS[nt] = __builtin_amdgcn_mfma_f32_16x16x32_bf16(kf0, qf0, accS[nt], 0, 0, 0);
      bf16x8 kf1 = *(const bf16x8*)&Ks1[cur][(nt * 16 + fm) * 32 + fs];
      accS[nt] = __builtin_amdgcn_mfma_f32_16x16x32_bf16(kf1, qf1, accS[nt], 0, 0, 0);
    }
    // softmax in-register; pack P^T B-frags immediately
    union { bf16x8 v; u32 u[4]; } P0, P1;
    float lps = 0.0f;
    float bnt = bias0;
    if (c < qt) {
      #pragma unroll
      for (int nt = 0; nt < 4; nt++) {
        float e0 = __builtin_amdgcn_exp2f(accS[nt][0] + bnt);
        float e1 = __builtin_amdgcn_exp2f((accS[nt][1] + sr1) + bnt);
        float e2 = __builtin_amdgcn_exp2f((accS[nt][2] + sr2) + bnt);
        float e3 = __builtin_amdgcn_exp2f((accS[nt][3] + sr3) + bnt);
        u32 w0 = pk2(e0, e1);
        u32 w1 = pk2(e2, e3);
        lps += (e0 + e1) + (e2 + e3);
        if (nt < 2) { P0.u[nt * 2] = w0; P0.u[nt * 2 + 1] = w1; }
        else        { P1.u[(nt - 2) * 2] = w0; P1.u[(nt - 2) * 2 + 1] = w1; }
        bnt += s16;
      }
    } else {
      // diagonal chunk: per-element causal mask (idx <= thr  <=>  jj <= q+2)
      int thr = q + 2 - jb;
      #pragma unroll
      for (int nt = 0; nt < 4; nt++) {
        int ib = nt * 16 + fg * 4;
        float e0 = __builtin_amdgcn_exp2f(accS[nt][0] + bnt);
        float e1 = __builtin_amdgcn_exp2f((accS[nt][1] + sr1) + bnt);
        float e2 = __builtin_amdgcn_exp2f((accS[nt][2] + sr2) + bnt);
        float e3 = __builtin_amdgcn_exp2f((accS[nt][3] + sr3) + bnt);
        e0 = (ib + 0 <= thr) ? e0 : 0.0f;
        e1 = (ib + 1 <= thr) ? e1 : 0.0f;
        e2 = (ib + 2 <= thr) ? e2 : 0.0f;
        e3 = (ib + 3 <= thr) ? e3 : 0.0f;
        u32 w0 = pk2(e0, e1);
        u32 w1 = pk2(e2, e3);
        lps += (e0 + e1) + (e2 + e3);
        if (nt < 2) { P0.u[nt * 2] = w0; P0.u[nt * 2 + 1] = w1; }
        else        { P1.u[(nt - 2) * 2] = w0; P1.u[(nt - 2) * 2 + 1] = w1; }
        bnt += s16;
      }
    }
    lp += lps;
    bias0 += d64;
    // wait V(c) only (leaves K(c+1) in flight); fenced barrier
    FENCED_WAIT_BAR("s_waitcnt vmcnt(2)")
    // O^T += V^T P^T
    #pragma unroll
    for (int nt = 0; nt < 4; nt++) {
      bf16x8 vf0 = *(const bf16x8*)&Vs0[(nt * 16 + fm) * 32 + fs];
      accO[nt] = __builtin_amdgcn_mfma_f32_16x16x32_bf16(vf0, P0.v, accO[nt], 0, 0, 0);
      bf16x8 vf1 = *(const bf16x8*)&Vs1[(nt * 16 + fm) * 32 + fs];
      accO[nt] = __builtin_amdgcn_mfma_f32_16x16x32_bf16(vf1, P1.v, accO[nt], 0, 0, 0);
    }
    // retire this wave's LDS reads, then barrier: no wave re-stages Vs/Ks[cur]
    // until every wave's reads have landed in registers.
    FENCED_WAIT_BAR("s_waitcnt lgkmcnt(0)")
    cur ^= 1;
  }
  lp += __shfl_xor(lp, 16, 64);
  lp += __shfl_xor(lp, 32, 64);
  // slot: [q 64][d 64] bf16 + l fp32[64]
  u16* P = partials + ((size_t)bh * NSEG_ + segid) * 4224;
  int sq = wv * 16 + fm;
  #pragma unroll
  for (int nt = 0; nt < 4; nt++) {
    uint2 ow;
    ow.x = pk2(accO[nt][0], accO[nt][1]);
    ow.y = pk2(accO[nt][2], accO[nt][3]);
    *(uint2*)(P + sq * 64 + nt * 16 + fg * 4) = ow;
  }
  if (fg == 0) *(float*)(P + 4096 + 2 * sq) = lp;
}

// ---------------- combine partials -> AO (b,n,h,d), 64-row tiles ----------------
__global__ __launch_bounds__(256) void comb_k(const u16* __restrict__ partials,
                                              u16* __restrict__ AO) {
  int qt = blockIdx.x, bh = blockIdx.y, b = bh >> 4, h = bh & 15;
  int t = threadIdx.x, q = t >> 2, dq = (t & 3) * 16;
  int s = (qt + 9) >> 3;
  int cum = 0;
  for (int tt = qt + 1; tt < 32; tt++) cum += (tt + 9) >> 3;
  float acc[16] = {};
  float lsum = 0.0f;
  for (int k = 0; k < s; k++) {
    const u16* P = partials + ((size_t)bh * NSEG_ + cum + k) * 4224;
    uint4 a = *(const uint4*)(P + q * 64 + dq);
    uint4 bq = *(const uint4*)(P + q * 64 + dq + 8);
    float tmp[8];
    unp8(a, tmp);
    #pragma unroll
    for (int e = 0; e < 8; e++) acc[e] += tmp[e];
    unp8(bq, tmp);
    #pragma unroll
    for (int e = 0; e < 8; e++) acc[8 + e] += tmp[e];
    lsum += *(const float*)(P + 4096 + 2 * q);
  }
  float linv = 1.0f / lsum;
  int n = qt * 64 + q;
  u16* dst = AO + (((size_t)(b * N_ + n)) * H_ + h) * 64 + dq;
  u16 ov[16] __attribute__((aligned(16)));
  #pragma unroll
  for (int e = 0; e < 16; e++) ov[e] = f2b(acc[e] * linv);
  *(uint4*)dst = ((uint4*)ov)[0];
  *(uint4*)(dst + 8) = ((uint4*)ov)[1];
}

// ---------------- launch ----------------
extern "C" void kernel_launch(void* const* d_in, const int* in_sizes, int n_in,
                              void* d_out, int out_size, void* d_ws, size_t ws_size,
                              hipStream_t stream) {
  const float* x    = (const float*)d_in[0];
  const float* ng   = (const float*)d_in[1];
  const float* nb   = (const float*)d_in[2];
  const float* Wq   = (const float*)d_in[3];
  const float* Wkv  = (const float*)d_in[4];
  const float* qs   = (const float*)d_in[5];
  const float* ks   = (const float*)d_in[6];
  const float* nkv  = (const float*)d_in[7];
  const float* Wout = (const float*)d_in[8];
  float* out = (float*)d_out;
  char* ws = (char*)d_ws;

  // layout (bytes):
  u16* xn    = (u16*)(ws + 0);            // 8,388,608 (AO reuses after Q-GEMM)
  u16* WoutT = (u16*)(ws + 8388608);      // 2,097,152
  u16* Qn    = (u16*)(ws + 10485760);     // 8,388,608
  u16* Kb    = (u16*)(ws + 18874368);     // 8,650,752 (JP stride)
  u16* VTp   = (u16*)(ws + 27525120);     // 8,650,752
  // overlay region @36175872 (dead by attn time):
  u16* xbf   = (u16*)(ws + 36175872);     // 8,388,608  (dead after KV-GEMM)
  u16* WqT   = (u16*)(ws + 44564480);     // 2,097,152  (dead after Q-GEMM)
  u16* WkvT  = (u16*)(ws + 46661632);     // 4,194,304  (dead after KV-GEMM)
  u16* parts = xbf;                       // 32*84*8448 = 22,708,224 (fits overlay)
  u16* AO    = xn;

  prep_k<<<dim3(259, 32), 256, 0, stream>>>(x, ng, nb, Wq, Wkv, Wout, nkv, ks,
                                            xn, xbf, WqT, WkvT, WoutT, Kb, VTp);
  gemmqkv_k<<<768, 256, 0, stream>>>(xn, WqT, xbf, WkvT, Qn, Kb, VTp, qs, ks);
  attn_k<<<dim3(NSEG_, 32), 256, 0, stream>>>(Qn, Kb, VTp, qs, ks, parts);
  comb_k<<<dim3(32, 32), 256, 0, stream>>>(parts, AO);
  gemm1_k<<<dim3(8, 32), 256, 0, stream>>>(AO, WoutT, out, M_, 1024, 1024);
}

// Round 13
// 197.225 us; speedup vs baseline: 1.0886x; 1.0674x over previous
//
#include <hip/hip_runtime.h>
#include <hip/hip_bf16.h>
#include <stdint.h>

// Problem constants
#define H_    16
#define N_    2048
#define DIM_  1024
#define DH_   64
#define NN_   2
#define J_    2050     // N + NNULL
#define JP_   2112     // 33*64, padded j (tails zeroed in prep)
#define B_    2
#define M_    4096     // B * N
#define NSEG_ 84       // sum over qt of ceil((qt+2)/8)  (64-row q-tiles)

#define S8L_  11.541560327111707f   // 8 * log2(e), folded into Qn at Q-GEMM epilogue
#define LOG2E_ 1.4426950408889634f

typedef unsigned short u16;
typedef unsigned int u32;
typedef short bf16x8 __attribute__((ext_vector_type(8)));
typedef float f32x4 __attribute__((ext_vector_type(4)));

__device__ __forceinline__ u16 f2b(float f) {
  union { float f; unsigned int i; } v; v.f = f;
  unsigned int r = v.i + 0x7fffu + ((v.i >> 16) & 1u);   // RNE
  return (u16)(r >> 16);
}
__device__ __forceinline__ float lo2f(u32 u) {
  union { u32 i; float f; } v; v.i = u << 16; return v.f;
}
__device__ __forceinline__ float hi2f(u32 u) {
  union { u32 i; float f; } v; v.i = u & 0xffff0000u; return v.f;
}
__device__ __forceinline__ void unp8(const uint4 u, float* d) {
  d[0] = lo2f(u.x); d[1] = hi2f(u.x); d[2] = lo2f(u.y); d[3] = hi2f(u.y);
  d[4] = lo2f(u.z); d[5] = hi2f(u.z); d[6] = lo2f(u.w); d[7] = hi2f(u.w);
}
// packed fp32x2 -> bf16x2 (single v_cvt_pk_bf16_f32)
__device__ __forceinline__ u32 pk2(float a, float b) {
  union { __hip_bfloat162 h; u32 u; } x;
  x.h = __float22bfloat162_rn(make_float2(a, b));
  return x.u;
}
// async global->LDS DMA, 16B/lane; LDS dest = wave-uniform base + lane*16
__device__ __forceinline__ void dma16(const u16* g, u16* l) {
  __builtin_amdgcn_global_load_lds(
      (const __attribute__((address_space(1))) u32*)(const void*)g,
      (__attribute__((address_space(3))) u32*)(void*)l, 16, 0, 0);
}

// fenced sync-point helper (R10-proven pattern: wait -> pin -> barrier -> pin)
#define FENCED_WAIT_BAR(WAITSTR)                     \
  asm volatile(WAITSTR ::: "memory");                \
  __builtin_amdgcn_sched_barrier(0);                 \
  __builtin_amdgcn_s_barrier();                      \
  __builtin_amdgcn_sched_barrier(0);

// ---------------- fused prep kernel ----------------
// bx <  128 : transpose+cast Wq/Wkv/Wout (fp32 RxC -> bf16 CxR)
// bx in [128,256): LayerNorm row (bx-128)*32+by -> xn, and bf16 cast -> xbf
// bx == 256 : null-kv rows j<2 -> Kb (l2norm*ks) and VTp (pos=j at c=0)
// bx == 257 : zero Kb rows j in [2048,2112) (j=2048,2049 overwritten by KV-GEMM after)
// bx == 258 : zero VTp chunk c=32 (pos 0,1 overwritten by KV-GEMM after)
__global__ __launch_bounds__(256) void prep_k(const float* __restrict__ x,
                                              const float* __restrict__ g,
                                              const float* __restrict__ bb,
                                              const float* __restrict__ Wq,
                                              const float* __restrict__ Wkv,
                                              const float* __restrict__ Wout,
                                              const float* __restrict__ nkv,
                                              const float* __restrict__ ks,
                                              u16* __restrict__ xn,
                                              u16* __restrict__ xbf,
                                              u16* __restrict__ WqT,
                                              u16* __restrict__ WkvT,
                                              u16* __restrict__ WoutT,
                                              u16* __restrict__ Kb,
                                              u16* __restrict__ VTp) {
  __shared__ float tile[32][33];
  __shared__ float red[8];
  int bx = blockIdx.x, by = blockIdx.y;
  int t = threadIdx.x;
  if (bx < 128) {
    // ---- weight transpose+cast ----
    const float* in; u16* out; int C; int cx;
    if (bx < 32)      { in = Wq;   out = WqT;   C = 1024; cx = bx; }
    else if (bx < 96) { in = Wkv;  out = WkvT;  C = 2048; cx = bx - 32; }
    else              { in = Wout; out = WoutT; C = 1024; cx = bx - 96; }
    const int R = 1024;
    int tx = t & 31, ty = t >> 5;   // 32 x 8
    int c0 = cx * 32, r0 = by * 32;
    #pragma unroll
    for (int i = 0; i < 32; i += 8)
      tile[ty + i][tx] = in[(size_t)(r0 + ty + i) * C + c0 + tx];
    __syncthreads();
    #pragma unroll
    for (int i = 0; i < 32; i += 8)
      out[(size_t)(c0 + ty + i) * R + r0 + tx] = f2b(tile[tx][ty + i]);
  } else if (bx < 256) {
    // ---- LayerNorm ----
    int row = (bx - 128) * 32 + by;
    float4 rw = *(const float4*)(x + (size_t)row * DIM_ + t * 4);
    float v0 = rw.x, v1 = rw.y, v2 = rw.z, v3 = rw.w;
    uint2 cw;
    cw.x = pk2(v0, v1);
    cw.y = pk2(v2, v3);
    *(uint2*)(xbf + (size_t)row * DIM_ + t * 4) = cw;
    float s = v0 + v1 + v2 + v3;
    float ss = v0 * v0 + v1 * v1 + v2 * v2 + v3 * v3;
    #pragma unroll
    for (int o = 32; o; o >>= 1) { s += __shfl_xor(s, o, 64); ss += __shfl_xor(ss, o, 64); }
    int lane = t & 63, w = t >> 6;
    if (lane == 0) { red[w] = s; red[4 + w] = ss; }
    __syncthreads();
    float S = red[0] + red[1] + red[2] + red[3];
    float SS = red[4] + red[5] + red[6] + red[7];
    float mu = S * (1.0f / DIM_);
    float var = SS * (1.0f / DIM_) - mu * mu;
    float rs = rsqrtf(var + 1e-5f);
    float4 gv = *(const float4*)(g + t * 4);
    float4 bv = *(const float4*)(bb + t * 4);
    uint2 ow;
    ow.x = pk2((v0 - mu) * rs * gv.x + bv.x, (v1 - mu) * rs * gv.y + bv.y);
    ow.y = pk2((v2 - mu) * rs * gv.z + bv.z, (v3 - mu) * rs * gv.w + bv.w);
    *(uint2*)(xn + (size_t)row * DIM_ + t * 4) = ow;
  } else if (bx == 256) {
    // ---- null kv: j = 0,1 ----
    int bh = by, h = bh & 15;
    if (t < 128) {
      int j = t >> 6, d = t & 63;
      float kv = nkv[(size_t)(h * 4 + 2 * j) * 64 + d];
      float vv = nkv[(size_t)(h * 4 + 2 * j + 1) * 64 + d];
      float ssp = kv * kv;
      #pragma unroll
      for (int o = 32; o; o >>= 1) ssp += __shfl_xor(ssp, o, 64);
      float inv = 1.0f / fmaxf(sqrtf(ssp), 1e-12f);
      Kb[((size_t)bh * JP_ + j) * 64 + d] = f2b(kv * inv * ks[d]);
      VTp[((size_t)bh * 64 + d) * JP_ + j] = f2b(vv);
    }
  } else if (bx == 257) {
    // ---- zero Kb rows j in [2048, 2112) ----
    int bh = by;
    uint4 z = {0, 0, 0, 0};
    u16* dst = Kb + ((size_t)bh * JP_ + 2048) * 64 + t * 16;
    ((uint4*)dst)[0] = z;
    ((uint4*)dst)[1] = z;
  } else {
    // ---- zero VTp chunk c=32 ----
    int bh = by;
    uint4 z = {0, 0, 0, 0};
    int d = t >> 2, p0 = (t & 3) * 16;
    u16* dst = VTp + ((size_t)bh * 64 + d) * JP_ + 2048 + p0;
    ((uint4*)dst)[0] = z;
    ((uint4*)dst)[1] = z;
  }
}

// ---------------- fused Q + KV GEMM, 128m x 64n tiles, BK=64, dbuf + counted vmcnt ----
// R12: 128x128 (64KB LDS -> 2 blocks/CU, occupancy 13.6%) shrunk to the R5-proven
//   128x64 tile: LDS 48KB dbuf -> 3 blocks/CU; grid 1536 (Q 512 + KV 1024) -> the
//   counted-vmcnt pipeline finally has TLP to overlap across barriers.
//   Per K-step/wave: stage 6 dma16 -> vmcnt(6) retires exactly buf[cur] -> fenced
//   barrier -> 8 ds_read + 16 MFMA -> lgkmcnt(0) + fenced barrier. Last iter vmcnt(0).
// nlin<512 -> Q (xn @ WqT -> Qn); else KV (xbf @ WkvT; K cols -> Kb; V cols -> VTp).
// 512%8==0 keeps both XCD y-chunk remaps bijective.
// pos(jl) = (jl>>5)*32 + ((jl>>2)&3)*8 + ((jl>>4)&1)*4 + (jl&3)   [pi inverse]
__global__ __launch_bounds__(256) void gemmqkv_k(const u16* __restrict__ xn,
                                                 const u16* __restrict__ WqT,
                                                 const u16* __restrict__ xbf,
                                                 const u16* __restrict__ WkvT,
                                                 u16* __restrict__ Qn,
                                                 u16* __restrict__ Kb,
                                                 u16* __restrict__ VTp,
                                                 const float* __restrict__ qs,
                                                 const float* __restrict__ ks) {
  __shared__ u16 As[2][128 * 64];   // 32 KB
  __shared__ u16 Bs[2][64 * 64];    // 16 KB
  const int K = 1024;
  int tid = threadIdx.x, wv = tid >> 6, lane = tid & 63;
  int fm = lane & 15, fg = lane >> 4;
  int fg4 = fg * 4;
  int nlin = (int)blockIdx.x;
  bool isQ = nlin < 512;
  const u16* A;
  const u16* BT;
  int gx, local;
  if (isQ) { A = xn;  BT = WqT;  gx = 16; local = nlin; }
  else     { A = xbf; BT = WkvT; gx = 32; local = nlin - 512; }
  // bijective XCD y-chunk remap within the sub-problem (local%8 == hw nlin%8)
  int mm = local >> 3;
  int row0 = ((local & 7) * 4 + mm / gx) * 128;
  int col0 = (mm % gx) * 64;
  f32x4 acc[2][4] = {};
  // staging geometry (R5): one dma16 = 8 rows x 128B; lane i -> row i>>3, kblk i&7
  int srow = lane >> 3;                 // 0..7
  int skb = ((lane & 7) ^ srow) * 8;    // swizzled global k-offset (u16)
  const u16* Ag = A + (size_t)(row0 + wv * 32 + srow) * K + skb;
  const u16* Bg = BT + (size_t)(col0 + wv * 16 + srow) * K + skb;
  // frag read offsets (row&7 == fm&7 since row = mult16 + fm)
  int fr7 = fm & 7;
  int ak0 = (fg ^ fr7) * 8;            // k-half 0: kblk = fg
  int ak1 = ((fg + 4) ^ fr7) * 8;      // k-half 1: kblk = fg + 4
  auto stageg = [&](int k0, int buf) {
    u16* AsW = As[buf] + (wv * 32) * 64;
    u16* BsW = Bs[buf] + (wv * 16) * 64;
    dma16(Ag + k0,                    AsW);
    dma16(Ag + (size_t)8 * K + k0,    AsW + 8 * 64);
    dma16(Ag + (size_t)16 * K + k0,   AsW + 16 * 64);
    dma16(Ag + (size_t)24 * K + k0,   AsW + 24 * 64);
    dma16(Bg + k0,                    BsW);
    dma16(Bg + (size_t)8 * K + k0,    BsW + 8 * 64);
  };
  stageg(0, 0);
  __builtin_amdgcn_sched_barrier(0);
  int cur = 0;
  #pragma unroll 1
  for (int k0 = 0; k0 < K; k0 += 64) {
    bool hasNext = (k0 + 64 < K);
    if (hasNext) stageg(k0 + 64, cur ^ 1);
    __builtin_amdgcn_sched_barrier(0);
    if (hasNext) {
      FENCED_WAIT_BAR("s_waitcnt vmcnt(6)")
    } else {
      FENCED_WAIT_BAR("s_waitcnt vmcnt(0)")
    }
    bf16x8 af0[2], af1[2], bf0[4], bf1[4];
    #pragma unroll
    for (int mt = 0; mt < 2; mt++) {
      int rbase = (wv * 32 + mt * 16 + fm) * 64;
      af0[mt] = *(const bf16x8*)&As[cur][rbase + ak0];
      af1[mt] = *(const bf16x8*)&As[cur][rbase + ak1];
    }
    #pragma unroll
    for (int nt = 0; nt < 4; nt++) {
      int rbase = (nt * 16 + fm) * 64;
      bf0[nt] = *(const bf16x8*)&Bs[cur][rbase + ak0];
      bf1[nt] = *(const bf16x8*)&Bs[cur][rbase + ak1];
    }
    #pragma unroll
    for (int mt = 0; mt < 2; mt++)
      #pragma unroll
      for (int nt = 0; nt < 4; nt++) {
        acc[mt][nt] = __builtin_amdgcn_mfma_f32_16x16x32_bf16(af0[mt], bf0[nt], acc[mt][nt], 0, 0, 0);
        acc[mt][nt] = __builtin_amdgcn_mfma_f32_16x16x32_bf16(af1[mt], bf1[nt], acc[mt][nt], 0, 0, 0);
      }
    // ds_reads retired to registers before any wave re-stages this buffer
    FENCED_WAIT_BAR("s_waitcnt lgkmcnt(0)")
    cur ^= 1;
  }
  // epilogue; tile's 64 cols = one head
  bool isK = isQ || (col0 < 1024);
  int h = (isK ? col0 : col0 - 1024) >> 6;
  if (isK) {
    const float* scale = isQ ? qs : ks;
    float sv[4];
    #pragma unroll
    for (int nt = 0; nt < 4; nt++) sv[nt] = scale[nt * 16 + fm];
    if (isQ) {
      #pragma unroll
      for (int nt = 0; nt < 4; nt++) sv[nt] *= S8L_;
    }
    u16* Do = isQ ? Qn : Kb;
    #pragma unroll
    for (int mt = 0; mt < 2; mt++) {
      #pragma unroll
      for (int r = 0; r < 4; r++) {
        float ssp = 0.0f;
        #pragma unroll
        for (int nt = 0; nt < 4; nt++) ssp += acc[mt][nt][r] * acc[mt][nt][r];
        #pragma unroll
        for (int o = 1; o <= 8; o <<= 1) ssp += __shfl_xor(ssp, o, 64);
        float inv = 1.0f / fmaxf(sqrtf(ssp), 1e-12f);
        int m = row0 + wv * 32 + mt * 16 + fg4 + r;
        int b = m >> 11, n = m & 2047;
        size_t base;
        if (isQ) base = (((size_t)(b * H_ + h)) * N_ + n) * 64;
        else     base = (((size_t)(b * H_ + h)) * JP_ + (n + NN_)) * 64;
        #pragma unroll
        for (int nt = 0; nt < 4; nt++)
          Do[base + nt * 16 + fm] = f2b(acc[mt][nt][r] * inv * sv[nt]);
      }
    }
  } else {
    // V -> VTp directly (permuted): VTp[(bh*64 + d)*JP + c*64 + pos(jl)], d = nt*16+fm
    #pragma unroll
    for (int mt = 0; mt < 2; mt++) {
      #pragma unroll
      for (int r = 0; r < 4; r++) {
        int m = row0 + wv * 32 + mt * 16 + fg4 + r;
        int b = m >> 11, n = m & 2047;
        int j = n + NN_;
        int c2 = j >> 6, jl = j & 63;
        int rem = jl & 31;
        int pos = (jl >> 5) * 32 + ((rem >> 2) & 3) * 8 + (rem >> 4) * 4 + (rem & 3);
        size_t hb = (size_t)(b * H_ + h) * 64;
        int off = c2 * 64 + pos;
        #pragma unroll
        for (int nt = 0; nt < 4; nt++)
          VTp[(hb + nt * 16 + fm) * JP_ + off] = f2b(acc[mt][nt][r]);
      }
    }
  }
}

// ---------------- out-projection GEMM: 128m x 64n tile, fp32 out, counted vmcnt ----
__global__ __launch_bounds__(256) void gemm1_k(const u16* __restrict__ A,
                                               const u16* __restrict__ BT,
                                               float* __restrict__ C,
                                               int M, int Nc, int K) {
  __shared__ u16 As[2][128 * 64];
  __shared__ u16 Bs[2][64 * 64];
  int tid = threadIdx.x, wv = tid >> 6, lane = tid & 63;
  int fm = lane & 15, fg = lane >> 4;
  int fg4 = fg * 4;
  int nlin = (int)blockIdx.x + (int)gridDim.x * (int)blockIdx.y;
  int gx = (int)gridDim.x;
  int mm = nlin >> 3;
  int row0 = ((nlin & 7) * 4 + mm / gx) * 128;
  int col0 = (mm % gx) * 64;
  f32x4 acc[2][4] = {};
  int srow = lane >> 3;
  int skb = ((lane & 7) ^ srow) * 8;
  const u16* Ag = A + (size_t)(row0 + wv * 32 + srow) * K + skb;
  const u16* Bg = BT + (size_t)(col0 + wv * 16 + srow) * K + skb;
  int fr7 = fm & 7;
  int ak0 = (fg ^ fr7) * 8;
  int ak1 = ((fg + 4) ^ fr7) * 8;
  auto stageg = [&](int k0, int buf) {
    u16* AsW = As[buf] + (wv * 32) * 64;
    u16* BsW = Bs[buf] + (wv * 16) * 64;
    dma16(Ag + k0,                    AsW);
    dma16(Ag + (size_t)8 * K + k0,    AsW + 8 * 64);
    dma16(Ag + (size_t)16 * K + k0,   AsW + 16 * 64);
    dma16(Ag + (size_t)24 * K + k0,   AsW + 24 * 64);
    dma16(Bg + k0,                    BsW);
    dma16(Bg + (size_t)8 * K + k0,    BsW + 8 * 64);
  };
  stageg(0, 0);
  __builtin_amdgcn_sched_barrier(0);
  int cur = 0;
  #pragma unroll 1
  for (int k0 = 0; k0 < K; k0 += 64) {
    bool hasNext = (k0 + 64 < K);
    if (hasNext) stageg(k0 + 64, cur ^ 1);
    __builtin_amdgcn_sched_barrier(0);
    if (hasNext) {
      FENCED_WAIT_BAR("s_waitcnt vmcnt(6)")
    } else {
      FENCED_WAIT_BAR("s_waitcnt vmcnt(0)")
    }
    bf16x8 af0[2], af1[2], bf0[4], bf1[4];
    #pragma unroll
    for (int mt = 0; mt < 2; mt++) {
      int rbase = (wv * 32 + mt * 16 + fm) * 64;
      af0[mt] = *(const bf16x8*)&As[cur][rbase + ak0];
      af1[mt] = *(const bf16x8*)&As[cur][rbase + ak1];
    }
    #pragma unroll
    for (int nt = 0; nt < 4; nt++) {
      int rbase = (nt * 16 + fm) * 64;
      bf0[nt] = *(const bf16x8*)&Bs[cur][rbase + ak0];
      bf1[nt] = *(const bf16x8*)&Bs[cur][rbase + ak1];
    }
    #pragma unroll
    for (int mt = 0; mt < 2; mt++)
      #pragma unroll
      for (int nt = 0; nt < 4; nt++) {
        acc[mt][nt] = __builtin_amdgcn_mfma_f32_16x16x32_bf16(af0[mt], bf0[nt], acc[mt][nt], 0, 0, 0);
        acc[mt][nt] = __builtin_amdgcn_mfma_f32_16x16x32_bf16(af1[mt], bf1[nt], acc[mt][nt], 0, 0, 0);
      }
    FENCED_WAIT_BAR("s_waitcnt lgkmcnt(0)")
    cur ^= 1;
  }
  #pragma unroll
  for (int mt = 0; mt < 2; mt++)
    #pragma unroll
    for (int r = 0; r < 4; r++) {
      int m = row0 + wv * 32 + mt * 16 + fg4 + r;
      #pragma unroll
      for (int nt = 0; nt < 4; nt++)
        C[(size_t)m * Nc + col0 + nt * 16 + fm] = acc[mt][nt][r];
    }
}

// ---------------- MFMA flash attention, 64-row q-tiles, counted-vmcnt pipeline -----
// R10 version unchanged (race-free fenced counted-vmcnt).
__global__ __launch_bounds__(256, 6) void attn_k(const u16* __restrict__ Qn,
                                                 const u16* __restrict__ Kb,
                                                 const u16* __restrict__ VTp,
                                                 const float* __restrict__ qs,
                                                 const float* __restrict__ ks,
                                                 u16* __restrict__ partials) {
  __shared__ u16 Ks0[2][64 * 32], Ks1[2][64 * 32];  // K dbuf: rows j, d 0..31 / 32..63
  __shared__ u16 Vs0[64 * 32], Vs1[64 * 32];        // V^T: rows d, j-pos 0..31 / 32..63
  int tid = threadIdx.x;
  int wv = tid >> 6, lane = tid & 63;
  int fm = lane & 15, fg = lane >> 4;
  // ---- T1 bijective XCD remap ----
  int n = (int)blockIdx.x + NSEG_ * (int)blockIdx.y;   // hw linear id (x-major)
  int m = n >> 3;                                      // 0..335
  int bh = (n & 7) * 4 + m / NSEG_;                    // 4 bh per XCD
  int segid = m % NSEG_;                               // segment within bh
  int h = bh & 15;
  // segment decode (qt descending)
  int cum = 0, qt = 0, seg = 0;
  #pragma unroll 1
  for (int i = 0; i < 32; i++) {
    int t = 31 - i, s = (t + 9) >> 3;
    if (segid < cum + s) { qt = t; seg = segid - cum; break; }
    cum += s;
  }
  int q0 = qt * 64;
  int q = q0 + wv * 16 + fm;
  float slope = exp2f(-0.5f * (float)(h + 1));
  float prod = fabsf(qs[lane] * ks[lane]);
  #pragma unroll
  for (int o = 32; o; o >>= 1) prod = fmaxf(prod, __shfl_xor(prod, o, 64));
  float MbL = 8.0f * prod * LOG2E_;          // max-bound, in log2 domain
  float slopeL = slope * LOG2E_;
  const u16* qp = Qn + ((size_t)bh * N_ + q) * 64 + fg * 8;
  bf16x8 qf0 = *(const bf16x8*)(qp);        // d 0..31 slice
  bf16x8 qf1 = *(const bf16x8*)(qp + 32);   // d 32..63 slice
  f32x4 accO[4] = {};
  float lp = 0.0f;
  int lr = lane >> 2;                                  // staging row 0..15
  int kbs = ((lane & 3) ^ ((lane >> 3) & 3)) * 8;      // swizzled staging k-offset
  int fs = (fg ^ ((fm >> 1) & 3)) * 8;                 // swizzled frag offset
  const u16* KbBH = Kb + (size_t)bh * JP_ * 64;
  const u16* VTbh = VTp + (size_t)bh * 64 * JP_;
  int c0 = seg * 8;
  int c1 = min(c0 + 8, qt + 2);
  // running bias scalars (log2 domain): bias0 at (chunk start, nt=0, r=0)
  float bias0 = slopeL * (float)(c0 * 64 + fg * 4 - q - 2) - MbL;
  float sr1 = slopeL, sr2 = slopeL * 2.0f, sr3 = slopeL * 3.0f;
  float s16 = slopeL * 16.0f;
  float d64 = slopeL * 64.0f;
  // ---- prologue: stage K(c0) into buffer 0; settle FIFO to exactly these 2 ----
  {
    const u16* Kg = KbBH + (size_t)(c0 * 64 + wv * 16 + lr) * 64 + kbs;
    dma16(Kg,      Ks0[0] + wv * 512);
    dma16(Kg + 32, Ks1[0] + wv * 512);
  }
  asm volatile("s_waitcnt vmcnt(2)" ::: "memory");   // all earlier loads (Qn/qs/ks) retired
  __builtin_amdgcn_sched_barrier(0);
  int cur = 0;
  #pragma unroll 1
  for (int c = c0; c < c1; c++) {
    int jb = c * 64;
    // issue V(c), then K(c+1) into the other K buffer (unconditional)
    const u16* Vg = VTbh + (size_t)(wv * 16 + lr) * JP_ + jb + kbs;
    dma16(Vg,      Vs0 + wv * 512);
    dma16(Vg + 32, Vs1 + wv * 512);
    const u16* Kg = KbBH + (size_t)(jb + 64 + wv * 16 + lr) * 64 + kbs;
    dma16(Kg,      Ks0[cur ^ 1] + wv * 512);
    dma16(Kg + 32, Ks1[cur ^ 1] + wv * 512);
    // wait K(c) only (leaves V(c), K(c+1) in flight); fenced barrier
    FENCED_WAIT_BAR("s_waitcnt vmcnt(4)")
    // S^T = K Q^T  (Qn pre-scaled by 8*log2e)
    f32x4 accS[4] = {};
    #pragma unroll
    for (int nt = 0; nt < 4; nt++) {
      bf16x8 kf0 = *(const bf16x8*)&Ks0[cur][(nt * 16 + fm) * 32 + fs];
      accS[nt] = __builtin_amdgcn_mfma_f32_16x16x32_bf16(kf0, qf0, accS[nt], 0, 0, 0);
      bf16x8 kf1 = *(const bf16x8*)&Ks1[cur][(nt * 16 + fm) * 32 + fs];
      accS[nt] = __builtin_amdgcn_mfma_f32_16x16x32_bf16(kf1, qf1, accS[nt], 0, 0, 0);
    }
    // softmax in-register; pack P^T B-frags immediately
    union { bf16x8 v; u32 u[4]; } P0, P1;
    float lps = 0.0f;
    float bnt = bias0;
    if (c < qt) {
      #pragma unroll
      for (int nt = 0; nt < 4; nt++) {
        float e0 = __builtin_amdgcn_exp2f(accS[nt][0] + bnt);
        float e1 = __builtin_amdgcn_exp2f((accS[nt][1] + sr1) + bnt);
        float e2 = __builtin_amdgcn_exp2f((accS[nt][2] + sr2) + bnt);
        float e3 = __builtin_amdgcn_exp2f((accS[nt][3] + sr3) + bnt);
        u32 w0 = pk2(e0, e1);
        u32 w1 = pk2(e2, e3);
        lps += (e0 + e1) + (e2 + e3);
        if (nt < 2) { P0.u[nt * 2] = w0; P0.u[nt * 2 + 1] = w1; }
        else        { P1.u[(nt - 2) * 2] = w0; P1.u[(nt - 2) * 2 + 1] = w1; }
        bnt += s16;
      }
    } else {
      // diagonal chunk: per-element causal mask (idx <= thr  <=>  jj <= q+2)
      int thr = q + 2 - jb;
      #pragma unroll
      for (int nt = 0; nt < 4; nt++) {
        int ib = nt * 16 + fg * 4;
        float e0 = __builtin_amdgcn_exp2f(accS[nt][0] + bnt);
        float e1 = __builtin_amdgcn_exp2f((accS[nt][1] + sr1) + bnt);
        float e2 = __builtin_amdgcn_exp2f((accS[nt][2] + sr2) + bnt);
        float e3 = __builtin_amdgcn_exp2f((accS[nt][3] + sr3) + bnt);
        e0 = (ib + 0 <= thr) ? e0 : 0.0f;
        e1 = (ib + 1 <= thr) ? e1 : 0.0f;
        e2 = (ib + 2 <= thr) ? e2 : 0.0f;
        e3 = (ib + 3 <= thr) ? e3 : 0.0f;
        u32 w0 = pk2(e0, e1);
        u32 w1 = pk2(e2, e3);
        lps += (e0 + e1) + (e2 + e3);
        if (nt < 2) { P0.u[nt * 2] = w0; P0.u[nt * 2 + 1] = w1; }
        else        { P1.u[(nt - 2) * 2] = w0; P1.u[(nt - 2) * 2 + 1] = w1; }
        bnt += s16;
      }
    }
    lp += lps;
    bias0 += d64;
    // wait V(c) only (leaves K(c+1) in flight); fenced barrier
    FENCED_WAIT_BAR("s_waitcnt vmcnt(2)")
    // O^T += V^T P^T
    #pragma unroll
    for (int nt = 0; nt < 4; nt++) {
      bf16x8 vf0 = *(const bf16x8*)&Vs0[(nt * 16 + fm) * 32 + fs];
      accO[nt] = __builtin_amdgcn_mfma_f32_16x16x32_bf16(vf0, P0.v, accO[nt], 0, 0, 0);
      bf16x8 vf1 = *(const bf16x8*)&Vs1[(nt * 16 + fm) * 32 + fs];
      accO[nt] = __builtin_amdgcn_mfma_f32_16x16x32_bf16(vf1, P1.v, accO[nt], 0, 0, 0);
    }
    // retire this wave's LDS reads, then barrier: no wave re-stages Vs/Ks[cur]
    // until every wave's reads have landed in registers.
    FENCED_WAIT_BAR("s_waitcnt lgkmcnt(0)")
    cur ^= 1;
  }
  lp += __shfl_xor(lp, 16, 64);
  lp += __shfl_xor(lp, 32, 64);
  // slot: [q 64][d 64] bf16 + l fp32[64]
  u16* P = partials + ((size_t)bh * NSEG_ + segid) * 4224;
  int sq = wv * 16 + fm;
  #pragma unroll
  for (int nt = 0; nt < 4; nt++) {
    uint2 ow;
    ow.x = pk2(accO[nt][0], accO[nt][1]);
    ow.y = pk2(accO[nt][2], accO[nt][3]);
    *(uint2*)(P + sq * 64 + nt * 16 + fg * 4) = ow;
  }
  if (fg == 0) *(float*)(P + 4096 + 2 * sq) = lp;
}

// ---------------- combine partials -> AO (b,n,h,d), 64-row tiles ----------------
__global__ __launch_bounds__(256) void comb_k(const u16* __restrict__ partials,
                                              u16* __restrict__ AO) {
  int qt = blockIdx.x, bh = blockIdx.y, b = bh >> 4, h = bh & 15;
  int t = threadIdx.x, q = t >> 2, dq = (t & 3) * 16;
  int s = (qt + 9) >> 3;
  int cum = 0;
  for (int tt = qt + 1; tt < 32; tt++) cum += (tt + 9) >> 3;
  float acc[16] = {};
  float lsum = 0.0f;
  for (int k = 0; k < s; k++) {
    const u16* P = partials + ((size_t)bh * NSEG_ + cum + k) * 4224;
    uint4 a = *(const uint4*)(P + q * 64 + dq);
    uint4 bq = *(const uint4*)(P + q * 64 + dq + 8);
    float tmp[8];
    unp8(a, tmp);
    #pragma unroll
    for (int e = 0; e < 8; e++) acc[e] += tmp[e];
    unp8(bq, tmp);
    #pragma unroll
    for (int e = 0; e < 8; e++) acc[8 + e] += tmp[e];
    lsum += *(const float*)(P + 4096 + 2 * q);
  }
  float linv = 1.0f / lsum;
  int n = qt * 64 + q;
  u16* dst = AO + (((size_t)(b * N_ + n)) * H_ + h) * 64 + dq;
  u16 ov[16] __attribute__((aligned(16)));
  #pragma unroll
  for (int e = 0; e < 16; e++) ov[e] = f2b(acc[e] * linv);
  *(uint4*)dst = ((uint4*)ov)[0];
  *(uint4*)(dst + 8) = ((uint4*)ov)[1];
}

// ---------------- launch ----------------
extern "C" void kernel_launch(void* const* d_in, const int* in_sizes, int n_in,
                              void* d_out, int out_size, void* d_ws, size_t ws_size,
                              hipStream_t stream) {
  const float* x    = (const float*)d_in[0];
  const float* ng   = (const float*)d_in[1];
  const float* nb   = (const float*)d_in[2];
  const float* Wq   = (const float*)d_in[3];
  const float* Wkv  = (const float*)d_in[4];
  const float* qs   = (const float*)d_in[5];
  const float* ks   = (const float*)d_in[6];
  const float* nkv  = (const float*)d_in[7];
  const float* Wout = (const float*)d_in[8];
  float* out = (float*)d_out;
  char* ws = (char*)d_ws;

  // layout (bytes):
  u16* xn    = (u16*)(ws + 0);            // 8,388,608 (AO reuses after Q-GEMM)
  u16* WoutT = (u16*)(ws + 8388608);      // 2,097,152
  u16* Qn    = (u16*)(ws + 10485760);     // 8,388,608
  u16* Kb    = (u16*)(ws + 18874368);     // 8,650,752 (JP stride)
  u16* VTp   = (u16*)(ws + 27525120);     // 8,650,752
  // overlay region @36175872 (dead by attn time):
  u16* xbf   = (u16*)(ws + 36175872);     // 8,388,608  (dead after KV-GEMM)
  u16* WqT   = (u16*)(ws + 44564480);     // 2,097,152  (dead after Q-GEMM)
  u16* WkvT  = (u16*)(ws + 46661632);     // 4,194,304  (dead after KV-GEMM)
  u16* parts = xbf;                       // 32*84*8448 = 22,708,224 (fits overlay)
  u16* AO    = xn;

  prep_k<<<dim3(259, 32), 256, 0, stream>>>(x, ng, nb, Wq, Wkv, Wout, nkv, ks,
                                            xn, xbf, WqT, WkvT, WoutT, Kb, VTp);
  gemmqkv_k<<<1536, 256, 0, stream>>>(xn, WqT, xbf, WkvT, Qn, Kb, VTp, qs, ks);
  attn_k<<<dim3(NSEG_, 32), 256, 0, stream>>>(Qn, Kb, VTp, qs, ks, parts);
  comb_k<<<dim3(32, 32), 256, 0, stream>>>(parts, AO);
  gemm1_k<<<dim3(16, 32), 256, 0, stream>>>(AO, WoutT, out, M_, 1024, 1024);
}